// Round 9
// baseline (467.830 us; speedup 1.0000x reference)
//
#include <hip/hip_runtime.h>
#include <hip/hip_bf16.h>

#define TOKENS 8192
#define KDIM 1024
#define NDIM 1024
#define NEXP 8

typedef __attribute__((ext_vector_type(8))) short short8v;
typedef __attribute__((ext_vector_type(8))) unsigned short ushort8v;
typedef __attribute__((ext_vector_type(4))) float f32x4;

__device__ inline unsigned short f2bf(float f) {
  unsigned int u = __float_as_uint(f);
  u += 0x7fffu + ((u >> 16) & 1u);
  return (unsigned short)(u >> 16);
}

__device__ inline void gload_lds16(const void* g, void* l) {
  __builtin_amdgcn_global_load_lds(
      (const __attribute__((address_space(1))) unsigned int*)g,
      (__attribute__((address_space(3))) unsigned int*)l, 16, 0, 0);
}

// ============================ FAST PATH ============================

// Fused: [0,256) gating + x->bf16; [256,4352) We->bf16.
__global__ __launch_bounds__(256) void gate_conv_kernel(
    const float* __restrict__ x, const float* __restrict__ Wg,
    const float* __restrict__ bg, const float* __restrict__ We,
    unsigned short* __restrict__ xb, unsigned short* __restrict__ Web,
    int* __restrict__ epacked, float2* __restrict__ wpair,
    int* __restrict__ hist) {
  int b = blockIdx.x;
  int tid = threadIdx.x;
  if (b >= 256) {
    size_t i = (size_t)(b - 256) * 256 + tid;
    const float4* s = reinterpret_cast<const float4*>(We + i * 8);
    float4 a = s[0], c = s[1];
    ushort8v v;
    v[0] = f2bf(a.x); v[1] = f2bf(a.y); v[2] = f2bf(a.z); v[3] = f2bf(a.w);
    v[4] = f2bf(c.x); v[5] = f2bf(c.y); v[6] = f2bf(c.z); v[7] = f2bf(c.w);
    *reinterpret_cast<ushort8v*>(Web + i * 8) = v;
    return;
  }
  __shared__ int lhist[16];
  if (tid < 16) lhist[tid] = 0;
  __syncthreads();
  int w = tid >> 6, lane = tid & 63;
  int tok0 = b * 32 + w * 8;

  for (int t = 0; t < 8; ++t) {
    int tok = tok0 + t;
    const float* xr = x + (size_t)tok * KDIM + lane * 16;
    float acc[NEXP] = {};
    ushort8v xv0, xv1;
#pragma unroll
    for (int j4 = 0; j4 < 4; ++j4) {
      float4 xv = *reinterpret_cast<const float4*>(xr + j4 * 4);
      float xs[4] = {xv.x, xv.y, xv.z, xv.w};
#pragma unroll
      for (int jj = 0; jj < 4; ++jj) {
        int k = lane * 16 + j4 * 4 + jj;
        const float4* wr = reinterpret_cast<const float4*>(Wg + k * NEXP);
        float4 w0 = wr[0], w1 = wr[1];
        float xf = xs[jj];
        acc[0] += xf * w0.x; acc[1] += xf * w0.y;
        acc[2] += xf * w0.z; acc[3] += xf * w0.w;
        acc[4] += xf * w1.x; acc[5] += xf * w1.y;
        acc[6] += xf * w1.z; acc[7] += xf * w1.w;
        int li = j4 * 4 + jj;
        unsigned short bv = f2bf(xf);
        if (li < 8) xv0[li] = bv; else xv1[li - 8] = bv;
      }
    }
    unsigned short* xrow = xb + (size_t)tok * KDIM + lane * 16;
    *reinterpret_cast<ushort8v*>(xrow) = xv0;
    *reinterpret_cast<ushort8v*>(xrow + 8) = xv1;
#pragma unroll
    for (int e = 0; e < NEXP; ++e) {
      acc[e] += __shfl_xor(acc[e], 1, 64);
      acc[e] += __shfl_xor(acc[e], 2, 64);
      acc[e] += __shfl_xor(acc[e], 4, 64);
      acc[e] += __shfl_xor(acc[e], 8, 64);
      acc[e] += __shfl_xor(acc[e], 16, 64);
      acc[e] += __shfl_xor(acc[e], 32, 64);
    }
    if (lane == 0) {
      float lg[NEXP];
#pragma unroll
      for (int e = 0; e < NEXP; ++e) lg[e] = acc[e] + bg[e];
      int e0 = 0;
#pragma unroll
      for (int e = 1; e < NEXP; ++e) if (lg[e] > lg[e0]) e0 = e;
      int e1 = -1;
#pragma unroll
      for (int e = 0; e < NEXP; ++e) {
        if (e == e0) continue;
        if (e1 < 0 || lg[e] > lg[e1]) e1 = e;
      }
      float tv = expf(lg[e1] - lg[e0]);
      float w0 = 1.0f / (1.0f + tv);
      float w1 = tv * w0;
      epacked[tok] = e0 | (e1 << 8);
      wpair[tok] = make_float2(w0, w1);
      atomicAdd(&lhist[e0], 1);
      atomicAdd(&lhist[8 + e1], 1);
    }
  }
  __syncthreads();
  if (tid < 16) hist[b * 16 + tid] = lhist[tid];
}

// scatter: per-block exclusive prefix over histograms -> routed lists.
__global__ __launch_bounds__(256) void scatter_kernel(
    const int* __restrict__ hist, const int* __restrict__ epacked,
    const float2* __restrict__ wpair, int* __restrict__ counts,
    int* __restrict__ lists, float* __restrict__ wlists) {
  __shared__ int partial[16][17];
  __shared__ int base[16];
  __shared__ int cnt2[16];
  int tid = threadIdx.x;
  int b = blockIdx.x;
  int bin = tid & 15, grp = tid >> 4;
  int s = 0;
  for (int i = 0; i < 16; ++i) {
    int bb = grp * 16 + i;
    if (bb < b) s += hist[bb * 16 + bin];
  }
  partial[grp][bin] = s;
  if (tid < 16) cnt2[tid] = 0;
  __syncthreads();
  if (tid < 16) {
    int s2 = 0;
#pragma unroll
    for (int g = 0; g < 16; ++g) s2 += partial[g][tid];
    base[tid] = s2;
  }
  __syncthreads();
  if (tid < 64) {
    int tok = b * 32 + (tid >> 1);
    int slot = tid & 1;
    int ep = epacked[tok];
    int e = slot ? ((ep >> 8) & 255) : (ep & 255);
    float2 wp = wpair[tok];
    float wv = slot ? wp.y : wp.x;
    int bn = slot * 8 + e;
    int pos = base[bn] + atomicAdd(&cnt2[bn], 1);
    lists[bn * TOKENS + pos] = tok;
    wlists[bn * TOKENS + pos] = wv;
  }
  if (b == 255) {
    __syncthreads();
    if (tid < 16) counts[tid] = base[tid] + cnt2[tid];
  }
}

// 256x256xBK64 grouped GEMM with 1024 threads / 16 waves (4M x 4N).
// Per-wave shape IDENTICAL to the proven 104-VGPR round-7 kernel:
// 64x64 out, acc[4][4] f32x4 = 64 VGPR. Forced cap for 1024-thr wg = 128. No spill.
// Counted-vmcnt 2-deep pipeline; plain slot-split stores (slot0->out, slot1->p1).
__global__ __launch_bounds__(1024) void moe_gemm_big(
    const unsigned short* __restrict__ xb, const unsigned short* __restrict__ Web,
    const float* __restrict__ be, const int* __restrict__ counts,
    const int* __restrict__ lists, const float* __restrict__ wlists,
    float* __restrict__ out, float* __restrict__ p1) {
  int bz = blockIdx.z;           // 0..15: slot*8 + expert
  int e = bz & 7;
  int slot = bz >> 3;
  int cnt = counts[bz];
  int mbase = blockIdx.y * 256;  // 8 M-tiles -> 2048-token capacity
  if (mbase >= cnt) return;
  int nbase = blockIdx.x * 256;  // 4 N-tiles
  const int* lst = lists + bz * TOKENS;
  const float* wl = wlists + bz * TOKENS;

  // [2 bufs][256 rows][64 cols] bf16; stored 16B-chunk cs at row r = logical cs^(r&7)
  __shared__ alignas(128) unsigned short lA[2][256 * 64];  // 64 KiB
  __shared__ alignas(128) unsigned short lB[2][256 * 64];  // 64 KiB

  int tid = threadIdx.x;         // 0..1023
  int lane = tid & 63;
  int w = tid >> 6;              // wave 0..15
  int wm = w >> 2, wn = w & 3;   // 4M x 4N waves; wave output 64x64
  int lm = lane & 15, lk = lane >> 4;

  // staging: 2 A + 2 B gload_lds16 per thread per K-tile (2048 chunks per tile)
  const unsigned short* aga[2];
  const unsigned short* bga[2];
#pragma unroll
  for (int j = 0; j < 2; ++j) {
    int L = j * 1024 + tid;       // chunk 0..2047
    int r = L >> 3, cs = L & 7;
    int c = cs ^ (r & 7);         // pre-swizzled global source (rule 21)
    int gr = mbase + r; if (gr >= cnt) gr = cnt - 1;
    aga[j] = xb + (size_t)lst[gr] * KDIM + c * 8;
    bga[j] = Web + (size_t)e * (NDIM * KDIM) + (size_t)(nbase + r) * KDIM + c * 8;
  }

#define STAGE(buf, kt)                                                         \
  {                                                                            \
    _Pragma("unroll") for (int j = 0; j < 2; ++j) {                            \
      gload_lds16(aga[j] + (kt) * 64, (char*)lA[buf] + j * 16384 + w * 1024);  \
      gload_lds16(bga[j] + (kt) * 64, (char*)lB[buf] + j * 16384 + w * 1024);  \
    }                                                                          \
  }

  f32x4 acc[4][4] = {};

#define COMPUTE(buf)                                                          \
  {                                                                           \
    _Pragma("unroll") for (int ks = 0; ks < 2; ++ks) {                        \
      short8v af[4], bfv[4];                                                  \
      _Pragma("unroll") for (int mi = 0; mi < 4; ++mi) {                      \
        int row = wm * 64 + mi * 16 + lm;                                     \
        int cs = (ks * 4 + lk) ^ (row & 7);                                   \
        af[mi] = *reinterpret_cast<const short8v*>(&lA[buf][row * 64 + cs * 8]); \
      }                                                                       \
      _Pragma("unroll") for (int nj = 0; nj < 4; ++nj) {                      \
        int row = wn * 64 + nj * 16 + lm;                                     \
        int cs = (ks * 4 + lk) ^ (row & 7);                                   \
        bfv[nj] = *reinterpret_cast<const short8v*>(&lB[buf][row * 64 + cs * 8]); \
      }                                                                       \
      asm volatile("s_waitcnt lgkmcnt(0)" ::: "memory");                      \
      __builtin_amdgcn_sched_barrier(0);                                      \
      __builtin_amdgcn_s_setprio(1);                                          \
      _Pragma("unroll") for (int mi = 0; mi < 4; ++mi)                        \
        _Pragma("unroll") for (int nj = 0; nj < 4; ++nj)                      \
          acc[mi][nj] = __builtin_amdgcn_mfma_f32_16x16x32_bf16(              \
              af[mi], bfv[nj], acc[mi][nj], 0, 0, 0);                         \
      __builtin_amdgcn_s_setprio(0);                                          \
    }                                                                         \
  }

  // prologue: 2 K-tiles in flight (4 loads/thread each)
  STAGE(0, 0);
  STAGE(1, 1);
  for (int kt = 0; kt < 15; ++kt) {
    asm volatile("s_waitcnt vmcnt(4)" ::: "memory");  // older tile's 4 done; newer 4 in flight
    asm volatile("s_barrier" ::: "memory");
    if ((kt & 1) == 0) COMPUTE(0) else COMPUTE(1);
    asm volatile("s_barrier" ::: "memory");           // all ds_reads done (lgkmcnt above)
    if (kt < 14) STAGE(kt & 1, kt + 2);
  }
  asm volatile("s_waitcnt vmcnt(0)" ::: "memory");
  asm volatile("s_barrier" ::: "memory");
  COMPUTE(1);
#undef STAGE
#undef COMPUTE

  // epilogue: C/D mapping col=lane&15, row=(lane>>4)*4+reg  [m89/m91]
  float* dst = slot ? p1 : out;
  float bev[4];
#pragma unroll
  for (int nj = 0; nj < 4; ++nj)
    bev[nj] = be[e * NDIM + nbase + wn * 64 + nj * 16 + lm];
#pragma unroll
  for (int mi = 0; mi < 4; ++mi) {
#pragma unroll
    for (int r = 0; r < 4; ++r) {
      int grow = mbase + wm * 64 + mi * 16 + lk * 4 + r;
      if (grow >= cnt) continue;
      int tokn = lst[grow];
      float wgt = wl[grow];
      float* orow = dst + (size_t)tokn * NDIM + nbase + wn * 64 + lm;
#pragma unroll
      for (int nj = 0; nj < 4; ++nj)
        orow[nj * 16] = wgt * (acc[mi][nj][r] + bev[nj]);
    }
  }
}

// out += p1 (both full disjoint single-writer covers)
__global__ __launch_bounds__(256) void combine_kernel(
    float* __restrict__ out, const float* __restrict__ p1) {
  size_t i = (size_t)blockIdx.x * 256 + threadIdx.x;
  float4 a = reinterpret_cast<const float4*>(p1)[i];
  float4 b = reinterpret_cast<float4*>(out)[i];
  b.x += a.x; b.y += a.y; b.z += a.z; b.w += a.w;
  reinterpret_cast<float4*>(out)[i] = b;
}

// ============================ MID PATH (round-7 proven) ============================

__global__ __launch_bounds__(256, 2) void moe_gemm_pipe(
    const unsigned short* __restrict__ xb, const unsigned short* __restrict__ Web,
    const float* __restrict__ be, const int* __restrict__ counts,
    const int* __restrict__ lists, const float* __restrict__ wlists,
    float* __restrict__ out) {
  int bz = blockIdx.z;
  int e = bz & 7;
  int cnt = counts[bz];
  int mbase = blockIdx.y * 128;
  if (mbase >= cnt) return;
  int nbase = blockIdx.x * 128;
  const int* lst = lists + bz * TOKENS;
  const float* wl = wlists + bz * TOKENS;
  __shared__ alignas(128) unsigned short lA[2][128 * 64];
  __shared__ alignas(128) unsigned short lB[2][128 * 64];
  int tid = threadIdx.x;
  int lane = tid & 63;
  int w = tid >> 6;
  int wm = w >> 1, wn = w & 1;
  int lm = lane & 15, lk = lane >> 4;
  const unsigned short* aga[4];
  const unsigned short* bga[4];
#pragma unroll
  for (int j = 0; j < 4; ++j) {
    int L = j * 256 + tid;
    int r = L >> 3, cs = L & 7;
    int c = cs ^ (r & 7);
    int gr = mbase + r; if (gr >= cnt) gr = cnt - 1;
    aga[j] = xb + (size_t)lst[gr] * KDIM + c * 8;
    bga[j] = Web + (size_t)e * (NDIM * KDIM) + (size_t)(nbase + r) * KDIM + c * 8;
  }
#define STAGE(buf, kt)                                                        \
  {                                                                           \
    _Pragma("unroll") for (int j = 0; j < 4; ++j) {                           \
      gload_lds16(aga[j] + (kt) * 64, (char*)lA[buf] + j * 4096 + w * 1024);  \
      gload_lds16(bga[j] + (kt) * 64, (char*)lB[buf] + j * 4096 + w * 1024);  \
    }                                                                         \
  }
  f32x4 acc[4][4] = {};
#define COMPUTE(buf)                                                          \
  {                                                                           \
    _Pragma("unroll") for (int ks = 0; ks < 2; ++ks) {                        \
      short8v af[4], bfv[4];                                                  \
      _Pragma("unroll") for (int mi = 0; mi < 4; ++mi) {                      \
        int row = wm * 64 + mi * 16 + lm;                                     \
        int cs = (ks * 4 + lk) ^ (row & 7);                                   \
        af[mi] = *reinterpret_cast<const short8v*>(&lA[buf][row * 64 + cs * 8]); \
      }                                                                       \
      _Pragma("unroll") for (int nj = 0; nj < 4; ++nj) {                      \
        int row = wn * 64 + nj * 16 + lm;                                     \
        int cs = (ks * 4 + lk) ^ (row & 7);                                   \
        bfv[nj] = *reinterpret_cast<const short8v*>(&lB[buf][row * 64 + cs * 8]); \
      }                                                                       \
      asm volatile("s_waitcnt lgkmcnt(0)" ::: "memory");                      \
      __builtin_amdgcn_sched_barrier(0);                                      \
      __builtin_amdgcn_s_setprio(1);                                          \
      _Pragma("unroll") for (int mi = 0; mi < 4; ++mi)                        \
        _Pragma("unroll") for (int nj = 0; nj < 4; ++nj)                      \
          acc[mi][nj] = __builtin_amdgcn_mfma_f32_16x16x32_bf16(              \
              af[mi], bfv[nj], acc[mi][nj], 0, 0, 0);                         \
      __builtin_amdgcn_s_setprio(0);                                          \
    }                                                                         \
  }
  STAGE(0, 0);
  STAGE(1, 1);
  for (int kt = 0; kt < 15; ++kt) {
    asm volatile("s_waitcnt vmcnt(8)" ::: "memory");
    asm volatile("s_barrier" ::: "memory");
    if ((kt & 1) == 0) COMPUTE(0) else COMPUTE(1);
    asm volatile("s_barrier" ::: "memory");
    if (kt < 14) STAGE(kt & 1, kt + 2);
  }
  asm volatile("s_waitcnt vmcnt(0)" ::: "memory");
  asm volatile("s_barrier" ::: "memory");
  COMPUTE(1);
#undef STAGE
#undef COMPUTE
  float bev[4];
#pragma unroll
  for (int nj = 0; nj < 4; ++nj)
    bev[nj] = be[e * NDIM + nbase + wn * 64 + nj * 16 + lm];
#pragma unroll
  for (int mi = 0; mi < 4; ++mi) {
#pragma unroll
    for (int r = 0; r < 4; ++r) {
      int grow = mbase + wm * 64 + mi * 16 + lk * 4 + r;
      if (grow >= cnt) continue;
      int tokn = lst[grow];
      float wgt = wl[grow];
      float* orow = out + (size_t)tokn * NDIM + nbase + wn * 64 + lm;
#pragma unroll
      for (int nj = 0; nj < 4; ++nj)
        unsafeAtomicAdd(&orow[nj * 16], wgt * (acc[mi][nj][r] + bev[nj]));
    }
  }
}

__global__ __launch_bounds__(256) void zero_out_kernel(float* __restrict__ out) {
  size_t i = (size_t)blockIdx.x * 256 + threadIdx.x;
  reinterpret_cast<float4*>(out)[i] = make_float4(0.f, 0.f, 0.f, 0.f);
}

// ============================ DEEP FALLBACK (round-1) ============================

__global__ __launch_bounds__(256) void gate_kernel(
    const float* __restrict__ x, const float* __restrict__ Wg,
    const float* __restrict__ bg, int* __restrict__ counts,
    int* __restrict__ lists, float* __restrict__ wlists) {
  int gtid = blockIdx.x * blockDim.x + threadIdx.x;
  int tok = gtid >> 6;
  int lane = threadIdx.x & 63;
  if (tok >= TOKENS) return;
  const float* xr = x + (size_t)tok * KDIM + lane * 16;
  float acc[NEXP] = {};
#pragma unroll
  for (int j4 = 0; j4 < 4; ++j4) {
    float4 xv = *reinterpret_cast<const float4*>(xr + j4 * 4);
    float xs[4] = {xv.x, xv.y, xv.z, xv.w};
#pragma unroll
    for (int jj = 0; jj < 4; ++jj) {
      int k = lane * 16 + j4 * 4 + jj;
      const float4* wr = reinterpret_cast<const float4*>(Wg + k * NEXP);
      float4 w0 = wr[0], w1 = wr[1];
      float xv1 = xs[jj];
      acc[0] += xv1 * w0.x; acc[1] += xv1 * w0.y;
      acc[2] += xv1 * w0.z; acc[3] += xv1 * w0.w;
      acc[4] += xv1 * w1.x; acc[5] += xv1 * w1.y;
      acc[6] += xv1 * w1.z; acc[7] += xv1 * w1.w;
    }
  }
#pragma unroll
  for (int e = 0; e < NEXP; ++e) {
    acc[e] += __shfl_xor(acc[e], 1, 64);
    acc[e] += __shfl_xor(acc[e], 2, 64);
    acc[e] += __shfl_xor(acc[e], 4, 64);
    acc[e] += __shfl_xor(acc[e], 8, 64);
    acc[e] += __shfl_xor(acc[e], 16, 64);
    acc[e] += __shfl_xor(acc[e], 32, 64);
  }
  if (lane == 0) {
    float lg[NEXP];
#pragma unroll
    for (int e = 0; e < NEXP; ++e) lg[e] = acc[e] + bg[e];
    int e0 = 0;
#pragma unroll
    for (int e = 1; e < NEXP; ++e) if (lg[e] > lg[e0]) e0 = e;
    int e1 = -1;
#pragma unroll
    for (int e = 0; e < NEXP; ++e) {
      if (e == e0) continue;
      if (e1 < 0 || lg[e] > lg[e1]) e1 = e;
    }
    float t = expf(lg[e1] - lg[e0]);
    float w0 = 1.0f / (1.0f + t);
    float w1 = t * w0;
    int p0 = atomicAdd(&counts[e0], 1);
    lists[e0 * TOKENS + p0] = tok;
    wlists[e0 * TOKENS + p0] = w0;
    int p1 = atomicAdd(&counts[NEXP + e1], 1);
    lists[(NEXP + e1) * TOKENS + p1] = tok;
    wlists[(NEXP + e1) * TOKENS + p1] = w1;
  }
}

template <int ACCUM>
__global__ __launch_bounds__(256) void moe_gemm(
    const float* __restrict__ x, const float* __restrict__ We,
    const float* __restrict__ be, const int* __restrict__ counts,
    const int* __restrict__ lists, const float* __restrict__ wlists,
    float* __restrict__ out, int slot) {
  int e = blockIdx.z;
  int cnt = counts[slot * NEXP + e];
  int mbase = blockIdx.y * 128;
  if (mbase >= cnt) return;
  int nbase = blockIdx.x * 128;
  const int* lst = lists + (slot * NEXP + e) * TOKENS;
  const float* wl = wlists + (slot * NEXP + e) * TOKENS;
  __shared__ ushort8v lA[1024];
  __shared__ ushort8v lB[1024];
  int tid = threadIdx.x;
  int lane = tid & 63;
  int w = tid >> 6;
  int wm = w >> 1, wn = w & 1;
  const float* aptr[4];
  const float* bptr[4];
  int sw[4];
#pragma unroll
  for (int i = 0; i < 4; ++i) {
    int c = i * 256 + tid;
    int r = c >> 3, cc = c & 7;
    int gr = mbase + r;
    if (gr >= cnt) gr = cnt - 1;
    int tokn = lst[gr];
    aptr[i] = x + (size_t)tokn * KDIM + cc * 8;
    bptr[i] = We + (size_t)e * (NDIM * KDIM) + (size_t)(nbase + r) * KDIM + cc * 8;
    sw[i] = r * 8 + (cc ^ (r & 7));
  }
  f32x4 acc[4][4] = {};
  int lm = lane & 15, lk = lane >> 4;
  for (int kt = 0; kt < KDIM / 64; ++kt) {
    __syncthreads();
#pragma unroll
    for (int i = 0; i < 4; ++i) {
      float4 f0 = *reinterpret_cast<const float4*>(aptr[i] + kt * 64);
      float4 f1 = *reinterpret_cast<const float4*>(aptr[i] + kt * 64 + 4);
      ushort8v v;
      v[0] = f2bf(f0.x); v[1] = f2bf(f0.y); v[2] = f2bf(f0.z); v[3] = f2bf(f0.w);
      v[4] = f2bf(f1.x); v[5] = f2bf(f1.y); v[6] = f2bf(f1.z); v[7] = f2bf(f1.w);
      lA[sw[i]] = v;
      float4 g0 = *reinterpret_cast<const float4*>(bptr[i] + kt * 64);
      float4 g1 = *reinterpret_cast<const float4*>(bptr[i] + kt * 64 + 4);
      ushort8v u;
      u[0] = f2bf(g0.x); u[1] = f2bf(g0.y); u[2] = f2bf(g0.z); u[3] = f2bf(g0.w);
      u[4] = f2bf(g1.x); u[5] = f2bf(g1.y); u[6] = f2bf(g1.z); u[7] = f2bf(g1.w);
      lB[sw[i]] = u;
    }
    __syncthreads();
#pragma unroll
    for (int ks = 0; ks < 2; ++ks) {
      short8v af[4], bfv[4];
#pragma unroll
      for (int mi = 0; mi < 4; ++mi) {
        int row = wm * 64 + mi * 16 + lm;
        int cidx = (ks * 4 + lk) ^ (row & 7);
        af[mi] = *reinterpret_cast<const short8v*>(&lA[row * 8 + cidx]);
      }
#pragma unroll
      for (int nj = 0; nj < 4; ++nj) {
        int row = wn * 64 + nj * 16 + lm;
        int cidx = (ks * 4 + lk) ^ (row & 7);
        bfv[nj] = *reinterpret_cast<const short8v*>(&lB[row * 8 + cidx]);
      }
#pragma unroll
      for (int mi = 0; mi < 4; ++mi)
#pragma unroll
        for (int nj = 0; nj < 4; ++nj)
          acc[mi][nj] = __builtin_amdgcn_mfma_f32_16x16x32_bf16(
              af[mi], bfv[nj], acc[mi][nj], 0, 0, 0);
    }
  }
  float bev[4];
#pragma unroll
  for (int nj = 0; nj < 4; ++nj)
    bev[nj] = be[e * NDIM + nbase + wn * 64 + nj * 16 + lm];
#pragma unroll
  for (int mi = 0; mi < 4; ++mi) {
#pragma unroll
    for (int r = 0; r < 4; ++r) {
      int grow = mbase + wm * 64 + mi * 16 + lk * 4 + r;
      if (grow >= cnt) continue;
      int tokn = lst[grow];
      float wgt = wl[grow];
      float* orow = out + (size_t)tokn * NDIM + nbase + wn * 64 + lm;
#pragma unroll
      for (int nj = 0; nj < 4; ++nj) {
        float val = wgt * (acc[mi][nj][r] + bev[nj]);
        if (ACCUM) orow[nj * 16] += val;
        else       orow[nj * 16] = val;
      }
    }
  }
}

// ============================ HOST ============================

extern "C" void kernel_launch(void* const* d_in, const int* in_sizes, int n_in,
                              void* d_out, int out_size, void* d_ws, size_t ws_size,
                              hipStream_t stream) {
  const float* x  = (const float*)d_in[0];
  const float* Wg = (const float*)d_in[1];
  const float* bg = (const float*)d_in[2];
  const float* We = (const float*)d_in[3];
  const float* be = (const float*)d_in[4];
  float* out = (float*)d_out;

  char* p = (char*)d_ws;
  int*   counts = (int*)p;                 p += 256;
  int*   lists  = (int*)p;                 p += (size_t)16 * TOKENS * 4;  // 512 KB
  float* wlists = (float*)p;               p += (size_t)16 * TOKENS * 4;  // 512 KB
  int*   epacked = (int*)p;                p += (size_t)TOKENS * 4;       // 32 KB
  float2* wpair  = (float2*)p;             p += (size_t)TOKENS * 8;       // 64 KB
  int*   hist    = (int*)p;                p += 256 * 16 * 4;             // 16 KB
  unsigned short* xbuf = (unsigned short*)p; p += (size_t)TOKENS * KDIM * 2;       // 16 MB
  unsigned short* Webf = (unsigned short*)p; p += (size_t)NEXP * NDIM * KDIM * 2;  // 16 MB
  size_t need_mid = (size_t)(p - (char*)d_ws);
  float* part1 = (float*)p;                p += (size_t)TOKENS * NDIM * 4;         // 32 MB
  size_t need_fast = (size_t)(p - (char*)d_ws);

  if (ws_size >= need_fast) {
    gate_conv_kernel<<<4352, 256, 0, stream>>>(
        x, Wg, bg, We, xbuf, Webf, epacked, wpair, hist);
    scatter_kernel<<<256, 256, 0, stream>>>(hist, epacked, wpair, counts, lists, wlists);
    dim3 grid(4, 8, 16);  // 4 N-tiles x 8 M-tiles (2048 cap) x 16 groups
    moe_gemm_big<<<grid, 1024, 0, stream>>>(
        xbuf, Webf, be, counts, lists, wlists, out, part1);
    combine_kernel<<<TOKENS * NDIM / 4 / 256, 256, 0, stream>>>(out, part1);
  } else if (ws_size >= need_mid) {
    zero_out_kernel<<<TOKENS * NDIM / 4 / 256, 256, 0, stream>>>(out);
    gate_conv_kernel<<<4352, 256, 0, stream>>>(
        x, Wg, bg, We, xbuf, Webf, epacked, wpair, hist);
    scatter_kernel<<<256, 256, 0, stream>>>(hist, epacked, wpair, counts, lists, wlists);
    dim3 grid(NDIM / 128, 16, 16);
    moe_gemm_pipe<<<grid, 256, 0, stream>>>(xbuf, Webf, be, counts, lists, wlists, out);
  } else {
    dim3 grid(NDIM / 128, TOKENS / 128, NEXP);
    hipMemsetAsync(d_ws, 0, 64, stream);
    gate_kernel<<<TOKENS / 4, 256, 0, stream>>>(x, Wg, bg, counts, lists, wlists);
    moe_gemm<0><<<grid, 256, 0, stream>>>(x, We, be, counts, lists, wlists, out, 0);
    moe_gemm<1><<<grid, 256, 0, stream>>>(x, We, be, counts, lists, wlists, out, 1);
  }
}

// Round 10
// 405.953 us; speedup vs baseline: 1.1524x; 1.1524x over previous
//
#include <hip/hip_runtime.h>
#include <hip/hip_bf16.h>

#define TOKENS 8192
#define KDIM 1024
#define NDIM 1024
#define NEXP 8

typedef __attribute__((ext_vector_type(8))) short short8v;
typedef __attribute__((ext_vector_type(8))) unsigned short ushort8v;
typedef __attribute__((ext_vector_type(4))) float f32x4;

__device__ inline unsigned short f2bf(float f) {
  unsigned int u = __float_as_uint(f);
  u += 0x7fffu + ((u >> 16) & 1u);
  return (unsigned short)(u >> 16);
}

__device__ inline void gload_lds16(const void* g, void* l) {
  __builtin_amdgcn_global_load_lds(
      (const __attribute__((address_space(1))) unsigned int*)g,
      (__attribute__((address_space(3))) unsigned int*)l, 16, 0, 0);
}

// ============================ FAST PATH ============================

// Fused: [0,256) gating + x->bf16; [256,4352) We->bf16; [4352,5376) zero out.
__global__ __launch_bounds__(256) void gate_conv_kernel(
    const float* __restrict__ x, const float* __restrict__ Wg,
    const float* __restrict__ bg, const float* __restrict__ We,
    unsigned short* __restrict__ xb, unsigned short* __restrict__ Web,
    int* __restrict__ epacked, float2* __restrict__ wpair,
    int* __restrict__ hist, float* __restrict__ out) {
  int b = blockIdx.x;
  int tid = threadIdx.x;
  if (b >= 4352) {
    float4* o = reinterpret_cast<float4*>(out) + (size_t)(b - 4352) * 2048 + tid;
    float4 z = make_float4(0.f, 0.f, 0.f, 0.f);
#pragma unroll
    for (int i = 0; i < 8; ++i) o[i * 256] = z;
    return;
  }
  if (b >= 256) {
    size_t i = (size_t)(b - 256) * 256 + tid;
    const float4* s = reinterpret_cast<const float4*>(We + i * 8);
    float4 a = s[0], c = s[1];
    ushort8v v;
    v[0] = f2bf(a.x); v[1] = f2bf(a.y); v[2] = f2bf(a.z); v[3] = f2bf(a.w);
    v[4] = f2bf(c.x); v[5] = f2bf(c.y); v[6] = f2bf(c.z); v[7] = f2bf(c.w);
    *reinterpret_cast<ushort8v*>(Web + i * 8) = v;
    return;
  }
  __shared__ int lhist[16];
  if (tid < 16) lhist[tid] = 0;
  __syncthreads();
  int w = tid >> 6, lane = tid & 63;
  int tok0 = b * 32 + w * 8;

  for (int t = 0; t < 8; ++t) {
    int tok = tok0 + t;
    const float* xr = x + (size_t)tok * KDIM + lane * 16;
    float acc[NEXP] = {};
    ushort8v xv0, xv1;
#pragma unroll
    for (int j4 = 0; j4 < 4; ++j4) {
      float4 xv = *reinterpret_cast<const float4*>(xr + j4 * 4);
      float xs[4] = {xv.x, xv.y, xv.z, xv.w};
#pragma unroll
      for (int jj = 0; jj < 4; ++jj) {
        int k = lane * 16 + j4 * 4 + jj;
        const float4* wr = reinterpret_cast<const float4*>(Wg + k * NEXP);
        float4 w0 = wr[0], w1 = wr[1];
        float xf = xs[jj];
        acc[0] += xf * w0.x; acc[1] += xf * w0.y;
        acc[2] += xf * w0.z; acc[3] += xf * w0.w;
        acc[4] += xf * w1.x; acc[5] += xf * w1.y;
        acc[6] += xf * w1.z; acc[7] += xf * w1.w;
        int li = j4 * 4 + jj;
        unsigned short bv = f2bf(xf);
        if (li < 8) xv0[li] = bv; else xv1[li - 8] = bv;
      }
    }
    unsigned short* xrow = xb + (size_t)tok * KDIM + lane * 16;
    *reinterpret_cast<ushort8v*>(xrow) = xv0;
    *reinterpret_cast<ushort8v*>(xrow + 8) = xv1;
#pragma unroll
    for (int e = 0; e < NEXP; ++e) {
      acc[e] += __shfl_xor(acc[e], 1, 64);
      acc[e] += __shfl_xor(acc[e], 2, 64);
      acc[e] += __shfl_xor(acc[e], 4, 64);
      acc[e] += __shfl_xor(acc[e], 8, 64);
      acc[e] += __shfl_xor(acc[e], 16, 64);
      acc[e] += __shfl_xor(acc[e], 32, 64);
    }
    if (lane == 0) {
      float lg[NEXP];
#pragma unroll
      for (int e = 0; e < NEXP; ++e) lg[e] = acc[e] + bg[e];
      int e0 = 0;
#pragma unroll
      for (int e = 1; e < NEXP; ++e) if (lg[e] > lg[e0]) e0 = e;
      int e1 = -1;
#pragma unroll
      for (int e = 0; e < NEXP; ++e) {
        if (e == e0) continue;
        if (e1 < 0 || lg[e] > lg[e1]) e1 = e;
      }
      float tv = expf(lg[e1] - lg[e0]);
      float w0 = 1.0f / (1.0f + tv);
      float w1 = tv * w0;
      epacked[tok] = e0 | (e1 << 8);
      wpair[tok] = make_float2(w0, w1);
      atomicAdd(&lhist[e0], 1);
      atomicAdd(&lhist[8 + e1], 1);
    }
  }
  __syncthreads();
  if (tid < 16) hist[b * 16 + tid] = lhist[tid];
}

// scatter: per-block exclusive prefix over histograms -> routed lists.
__global__ __launch_bounds__(256) void scatter_kernel(
    const int* __restrict__ hist, const int* __restrict__ epacked,
    const float2* __restrict__ wpair, int* __restrict__ counts,
    int* __restrict__ lists, float* __restrict__ wlists) {
  __shared__ int partial[16][17];
  __shared__ int base[16];
  __shared__ int cnt2[16];
  int tid = threadIdx.x;
  int b = blockIdx.x;
  int bin = tid & 15, grp = tid >> 4;
  int s = 0;
  for (int i = 0; i < 16; ++i) {
    int bb = grp * 16 + i;
    if (bb < b) s += hist[bb * 16 + bin];
  }
  partial[grp][bin] = s;
  if (tid < 16) cnt2[tid] = 0;
  __syncthreads();
  if (tid < 16) {
    int s2 = 0;
#pragma unroll
    for (int g = 0; g < 16; ++g) s2 += partial[g][tid];
    base[tid] = s2;
  }
  __syncthreads();
  if (tid < 64) {
    int tok = b * 32 + (tid >> 1);
    int slot = tid & 1;
    int ep = epacked[tok];
    int e = slot ? ((ep >> 8) & 255) : (ep & 255);
    float2 wp = wpair[tok];
    float wv = slot ? wp.y : wp.x;
    int bn = slot * 8 + e;
    int pos = base[bn] + atomicAdd(&cnt2[bn], 1);
    lists[bn * TOKENS + pos] = tok;
    wlists[bn * TOKENS + pos] = wv;
  }
  if (b == 255) {
    __syncthreads();
    if (tid < 16) counts[tid] = base[tid] + cnt2[tid];
  }
}

// 256x256xBK64 grouped GEMM, 512 threads / 8 waves (2M x 4N, wave out 128x64).
// __launch_bounds__(512, 1): block forces 2 waves/SIMD -> 256-VGPR cap; the
// explicit min-waves=1 stops the allocator's 4-wave/128-VGPR heuristic that
// spilled acc in r5/r8/r9 (scratch = the 500+MB WRITE_SIZE).
// Counted-vmcnt 2-deep pipeline; r4-proven atomic epilogue (out pre-zeroed).
__global__ __launch_bounds__(512, 1) void moe_gemm_big(
    const unsigned short* __restrict__ xb, const unsigned short* __restrict__ Web,
    const float* __restrict__ be, const int* __restrict__ counts,
    const int* __restrict__ lists, const float* __restrict__ wlists,
    float* __restrict__ out) {
  int bz = blockIdx.z;           // slot*8 + expert
  int e = bz & 7;
  int cnt = counts[bz];
  int mbase = blockIdx.y * 256;  // 8 M-tiles -> 2048-token capacity
  if (mbase >= cnt) return;
  int nbase = blockIdx.x * 256;  // 4 N-tiles
  const int* lst = lists + bz * TOKENS;
  const float* wl = wlists + bz * TOKENS;

  // [2 bufs][256 rows][64 cols] bf16; stored 16B-chunk cs at row r = logical cs^(r&7)
  __shared__ alignas(128) unsigned short lA[2][256 * 64];  // 64 KiB
  __shared__ alignas(128) unsigned short lB[2][256 * 64];  // 64 KiB

  int tid = threadIdx.x;         // 0..511
  int lane = tid & 63;
  int w = tid >> 6;              // wave 0..7
  int wm = w >> 2, wn = w & 3;   // 2M x 4N; wave output 128x64
  int lm = lane & 15, lk = lane >> 4;

  const unsigned short* aga[4];
  const unsigned short* bga[4];
#pragma unroll
  for (int j = 0; j < 4; ++j) {
    int L = j * 512 + tid;        // chunk 0..2047 (256 rows x 8 chunks)
    int r = L >> 3, cs = L & 7;
    int c = cs ^ (r & 7);         // pre-swizzled global source (rule 21)
    int gr = mbase + r; if (gr >= cnt) gr = cnt - 1;
    aga[j] = xb + (size_t)lst[gr] * KDIM + c * 8;
    bga[j] = Web + (size_t)e * (NDIM * KDIM) + (size_t)(nbase + r) * KDIM + c * 8;
  }

#define STAGE(buf, kt)                                                        \
  {                                                                           \
    _Pragma("unroll") for (int j = 0; j < 4; ++j) {                           \
      gload_lds16(aga[j] + (kt) * 64, (char*)lA[buf] + j * 8192 + w * 1024);  \
      gload_lds16(bga[j] + (kt) * 64, (char*)lB[buf] + j * 8192 + w * 1024);  \
    }                                                                         \
  }

  f32x4 acc[8][4] = {};

#define COMPUTE(buf)                                                          \
  {                                                                           \
    _Pragma("unroll") for (int ks = 0; ks < 2; ++ks) {                        \
      short8v af[8], bfv[4];                                                  \
      _Pragma("unroll") for (int mi = 0; mi < 8; ++mi) {                      \
        int row = wm * 128 + mi * 16 + lm;                                    \
        int cs = (ks * 4 + lk) ^ (row & 7);                                   \
        af[mi] = *reinterpret_cast<const short8v*>(&lA[buf][row * 64 + cs * 8]); \
      }                                                                       \
      _Pragma("unroll") for (int nj = 0; nj < 4; ++nj) {                      \
        int row = wn * 64 + nj * 16 + lm;                                     \
        int cs = (ks * 4 + lk) ^ (row & 7);                                   \
        bfv[nj] = *reinterpret_cast<const short8v*>(&lB[buf][row * 64 + cs * 8]); \
      }                                                                       \
      asm volatile("s_waitcnt lgkmcnt(0)" ::: "memory");                      \
      __builtin_amdgcn_sched_barrier(0);                                      \
      __builtin_amdgcn_s_setprio(1);                                          \
      _Pragma("unroll") for (int mi = 0; mi < 8; ++mi)                        \
        _Pragma("unroll") for (int nj = 0; nj < 4; ++nj)                      \
          acc[mi][nj] = __builtin_amdgcn_mfma_f32_16x16x32_bf16(              \
              af[mi], bfv[nj], acc[mi][nj], 0, 0, 0);                         \
      __builtin_amdgcn_s_setprio(0);                                          \
    }                                                                         \
  }

  STAGE(0, 0);
  STAGE(1, 1);
  for (int kt = 0; kt < 15; ++kt) {
    asm volatile("s_waitcnt vmcnt(8)" ::: "memory");  // older tile's 8 done; newer in flight
    asm volatile("s_barrier" ::: "memory");
    if ((kt & 1) == 0) COMPUTE(0) else COMPUTE(1);
    asm volatile("s_barrier" ::: "memory");           // all ds_reads done (lgkmcnt above)
    if (kt < 14) STAGE(kt & 1, kt + 2);
  }
  asm volatile("s_waitcnt vmcnt(0)" ::: "memory");
  asm volatile("s_barrier" ::: "memory");
  COMPUTE(1);
#undef STAGE
#undef COMPUTE

  // epilogue: C/D mapping col=lane&15, row=(lane>>4)*4+reg  [m89/m91]
  float bev[4];
#pragma unroll
  for (int nj = 0; nj < 4; ++nj)
    bev[nj] = be[e * NDIM + nbase + wn * 64 + nj * 16 + lm];
#pragma unroll
  for (int mi = 0; mi < 8; ++mi) {
#pragma unroll
    for (int r = 0; r < 4; ++r) {
      int grow = mbase + wm * 128 + mi * 16 + lk * 4 + r;
      if (grow >= cnt) continue;
      int tokn = lst[grow];
      float wgt = wl[grow];
      float* orow = out + (size_t)tokn * NDIM + nbase + wn * 64 + lm;
#pragma unroll
      for (int nj = 0; nj < 4; ++nj)
        unsafeAtomicAdd(&orow[nj * 16], wgt * (acc[mi][nj][r] + bev[nj]));
    }
  }
}

// ============================ DEEP FALLBACK (round-1) ============================

__global__ __launch_bounds__(256) void gate_kernel(
    const float* __restrict__ x, const float* __restrict__ Wg,
    const float* __restrict__ bg, int* __restrict__ counts,
    int* __restrict__ lists, float* __restrict__ wlists) {
  int gtid = blockIdx.x * blockDim.x + threadIdx.x;
  int tok = gtid >> 6;
  int lane = threadIdx.x & 63;
  if (tok >= TOKENS) return;
  const float* xr = x + (size_t)tok * KDIM + lane * 16;
  float acc[NEXP] = {};
#pragma unroll
  for (int j4 = 0; j4 < 4; ++j4) {
    float4 xv = *reinterpret_cast<const float4*>(xr + j4 * 4);
    float xs[4] = {xv.x, xv.y, xv.z, xv.w};
#pragma unroll
    for (int jj = 0; jj < 4; ++jj) {
      int k = lane * 16 + j4 * 4 + jj;
      const float4* wr = reinterpret_cast<const float4*>(Wg + k * NEXP);
      float4 w0 = wr[0], w1 = wr[1];
      float xv1 = xs[jj];
      acc[0] += xv1 * w0.x; acc[1] += xv1 * w0.y;
      acc[2] += xv1 * w0.z; acc[3] += xv1 * w0.w;
      acc[4] += xv1 * w1.x; acc[5] += xv1 * w1.y;
      acc[6] += xv1 * w1.z; acc[7] += xv1 * w1.w;
    }
  }
#pragma unroll
  for (int e = 0; e < NEXP; ++e) {
    acc[e] += __shfl_xor(acc[e], 1, 64);
    acc[e] += __shfl_xor(acc[e], 2, 64);
    acc[e] += __shfl_xor(acc[e], 4, 64);
    acc[e] += __shfl_xor(acc[e], 8, 64);
    acc[e] += __shfl_xor(acc[e], 16, 64);
    acc[e] += __shfl_xor(acc[e], 32, 64);
  }
  if (lane == 0) {
    float lg[NEXP];
#pragma unroll
    for (int e = 0; e < NEXP; ++e) lg[e] = acc[e] + bg[e];
    int e0 = 0;
#pragma unroll
    for (int e = 1; e < NEXP; ++e) if (lg[e] > lg[e0]) e0 = e;
    int e1 = -1;
#pragma unroll
    for (int e = 0; e < NEXP; ++e) {
      if (e == e0) continue;
      if (e1 < 0 || lg[e] > lg[e1]) e1 = e;
    }
    float t = expf(lg[e1] - lg[e0]);
    float w0 = 1.0f / (1.0f + t);
    float w1 = t * w0;
    int p0 = atomicAdd(&counts[e0], 1);
    lists[e0 * TOKENS + p0] = tok;
    wlists[e0 * TOKENS + p0] = w0;
    int p1 = atomicAdd(&counts[NEXP + e1], 1);
    lists[(NEXP + e1) * TOKENS + p1] = tok;
    wlists[(NEXP + e1) * TOKENS + p1] = w1;
  }
}

template <int ACCUM>
__global__ __launch_bounds__(256) void moe_gemm(
    const float* __restrict__ x, const float* __restrict__ We,
    const float* __restrict__ be, const int* __restrict__ counts,
    const int* __restrict__ lists, const float* __restrict__ wlists,
    float* __restrict__ out, int slot) {
  int e = blockIdx.z;
  int cnt = counts[slot * NEXP + e];
  int mbase = blockIdx.y * 128;
  if (mbase >= cnt) return;
  int nbase = blockIdx.x * 128;
  const int* lst = lists + (slot * NEXP + e) * TOKENS;
  const float* wl = wlists + (slot * NEXP + e) * TOKENS;
  __shared__ ushort8v lA[1024];
  __shared__ ushort8v lB[1024];
  int tid = threadIdx.x;
  int lane = tid & 63;
  int w = tid >> 6;
  int wm = w >> 1, wn = w & 1;
  const float* aptr[4];
  const float* bptr[4];
  int sw[4];
#pragma unroll
  for (int i = 0; i < 4; ++i) {
    int c = i * 256 + tid;
    int r = c >> 3, cc = c & 7;
    int gr = mbase + r;
    if (gr >= cnt) gr = cnt - 1;
    int tokn = lst[gr];
    aptr[i] = x + (size_t)tokn * KDIM + cc * 8;
    bptr[i] = We + (size_t)e * (NDIM * KDIM) + (size_t)(nbase + r) * KDIM + cc * 8;
    sw[i] = r * 8 + (cc ^ (r & 7));
  }
  f32x4 acc[4][4] = {};
  int lm = lane & 15, lk = lane >> 4;
  for (int kt = 0; kt < KDIM / 64; ++kt) {
    __syncthreads();
#pragma unroll
    for (int i = 0; i < 4; ++i) {
      float4 f0 = *reinterpret_cast<const float4*>(aptr[i] + kt * 64);
      float4 f1 = *reinterpret_cast<const float4*>(aptr[i] + kt * 64 + 4);
      ushort8v v;
      v[0] = f2bf(f0.x); v[1] = f2bf(f0.y); v[2] = f2bf(f0.z); v[3] = f2bf(f0.w);
      v[4] = f2bf(f1.x); v[5] = f2bf(f1.y); v[6] = f2bf(f1.z); v[7] = f2bf(f1.w);
      lA[sw[i]] = v;
      float4 g0 = *reinterpret_cast<const float4*>(bptr[i] + kt * 64);
      float4 g1 = *reinterpret_cast<const float4*>(bptr[i] + kt * 64 + 4);
      ushort8v u;
      u[0] = f2bf(g0.x); u[1] = f2bf(g0.y); u[2] = f2bf(g0.z); u[3] = f2bf(g0.w);
      u[4] = f2bf(g1.x); u[5] = f2bf(g1.y); u[6] = f2bf(g1.z); u[7] = f2bf(g1.w);
      lB[sw[i]] = u;
    }
    __syncthreads();
#pragma unroll
    for (int ks = 0; ks < 2; ++ks) {
      short8v af[4], bfv[4];
#pragma unroll
      for (int mi = 0; mi < 4; ++mi) {
        int row = wm * 64 + mi * 16 + lm;
        int cidx = (ks * 4 + lk) ^ (row & 7);
        af[mi] = *reinterpret_cast<const short8v*>(&lA[row * 8 + cidx]);
      }
#pragma unroll
      for (int nj = 0; nj < 4; ++nj) {
        int row = wn * 64 + nj * 16 + lm;
        int cidx = (ks * 4 + lk) ^ (row & 7);
        bfv[nj] = *reinterpret_cast<const short8v*>(&lB[row * 8 + cidx]);
      }
#pragma unroll
      for (int mi = 0; mi < 4; ++mi)
#pragma unroll
        for (int nj = 0; nj < 4; ++nj)
          acc[mi][nj] = __builtin_amdgcn_mfma_f32_16x16x32_bf16(
              af[mi], bfv[nj], acc[mi][nj], 0, 0, 0);
    }
  }
  float bev[4];
#pragma unroll
  for (int nj = 0; nj < 4; ++nj)
    bev[nj] = be[e * NDIM + nbase + wn * 64 + nj * 16 + lm];
#pragma unroll
  for (int mi = 0; mi < 4; ++mi) {
#pragma unroll
    for (int r = 0; r < 4; ++r) {
      int grow = mbase + wm * 64 + mi * 16 + lk * 4 + r;
      if (grow >= cnt) continue;
      int tokn = lst[grow];
      float wgt = wl[grow];
      float* orow = out + (size_t)tokn * NDIM + nbase + wn * 64 + lm;
#pragma unroll
      for (int nj = 0; nj < 4; ++nj) {
        float val = wgt * (acc[mi][nj][r] + bev[nj]);
        if (ACCUM) orow[nj * 16] += val;
        else       orow[nj * 16] = val;
      }
    }
  }
}

// ============================ HOST ============================

extern "C" void kernel_launch(void* const* d_in, const int* in_sizes, int n_in,
                              void* d_out, int out_size, void* d_ws, size_t ws_size,
                              hipStream_t stream) {
  const float* x  = (const float*)d_in[0];
  const float* Wg = (const float*)d_in[1];
  const float* bg = (const float*)d_in[2];
  const float* We = (const float*)d_in[3];
  const float* be = (const float*)d_in[4];
  float* out = (float*)d_out;

  char* p = (char*)d_ws;
  int*   counts = (int*)p;                 p += 256;
  int*   lists  = (int*)p;                 p += (size_t)16 * TOKENS * 4;  // 512 KB
  float* wlists = (float*)p;               p += (size_t)16 * TOKENS * 4;  // 512 KB
  int*   epacked = (int*)p;                p += (size_t)TOKENS * 4;       // 32 KB
  float2* wpair  = (float2*)p;             p += (size_t)TOKENS * 8;       // 64 KB
  int*   hist    = (int*)p;                p += 256 * 16 * 4;             // 16 KB
  unsigned short* xbuf = (unsigned short*)p; p += (size_t)TOKENS * KDIM * 2;       // 16 MB
  unsigned short* Webf = (unsigned short*)p; p += (size_t)NEXP * NDIM * KDIM * 2;  // 16 MB
  size_t need = (size_t)(p - (char*)d_ws);

  if (ws_size >= need) {
    gate_conv_kernel<<<5376, 256, 0, stream>>>(
        x, Wg, bg, We, xbuf, Webf, epacked, wpair, hist, out);
    scatter_kernel<<<256, 256, 0, stream>>>(hist, epacked, wpair, counts, lists, wlists);
    dim3 grid(4, 8, 16);  // 4 N-tiles x 8 M-tiles (2048 cap) x 16 groups = 512 blocks
    moe_gemm_big<<<grid, 512, 0, stream>>>(xbuf, Webf, be, counts, lists, wlists, out);
  } else {
    dim3 grid(NDIM / 128, TOKENS / 128, NEXP);
    hipMemsetAsync(d_ws, 0, 64, stream);
    gate_kernel<<<TOKENS / 4, 256, 0, stream>>>(x, Wg, bg, counts, lists, wlists);
    moe_gemm<0><<<grid, 256, 0, stream>>>(x, We, be, counts, lists, wlists, out, 0);
    moe_gemm<1><<<grid, 256, 0, stream>>>(x, We, be, counts, lists, wlists, out, 1);
  }
}

// Round 11
// 330.674 us; speedup vs baseline: 1.4148x; 1.2277x over previous
//
#include <hip/hip_runtime.h>
#include <hip/hip_bf16.h>

#define TOKENS 8192
#define KDIM 1024
#define NDIM 1024
#define NEXP 8

typedef __attribute__((ext_vector_type(8))) short short8v;
typedef __attribute__((ext_vector_type(8))) unsigned short ushort8v;
typedef __attribute__((ext_vector_type(4))) float f32x4;

__device__ inline unsigned short f2bf(float f) {
  unsigned int u = __float_as_uint(f);
  u += 0x7fffu + ((u >> 16) & 1u);
  return (unsigned short)(u >> 16);
}

__device__ inline void gload_lds16(const void* g, void* l) {
  __builtin_amdgcn_global_load_lds(
      (const __attribute__((address_space(1))) unsigned int*)g,
      (__attribute__((address_space(3))) unsigned int*)l, 16, 0, 0);
}

// ============================ FAST PATH ============================

// Fused: [0,256) gating + x->bf16; [256,4352) We->bf16; [4352,5376) zero out.
__global__ __launch_bounds__(256) void gate_conv_kernel(
    const float* __restrict__ x, const float* __restrict__ Wg,
    const float* __restrict__ bg, const float* __restrict__ We,
    unsigned short* __restrict__ xb, unsigned short* __restrict__ Web,
    int* __restrict__ epacked, float2* __restrict__ wpair,
    int* __restrict__ hist, float* __restrict__ out) {
  int b = blockIdx.x;
  int tid = threadIdx.x;
  if (b >= 4352) {
    float4* o = reinterpret_cast<float4*>(out) + (size_t)(b - 4352) * 2048 + tid;
    float4 z = make_float4(0.f, 0.f, 0.f, 0.f);
#pragma unroll
    for (int i = 0; i < 8; ++i) o[i * 256] = z;
    return;
  }
  if (b >= 256) {
    size_t i = (size_t)(b - 256) * 256 + tid;
    const float4* s = reinterpret_cast<const float4*>(We + i * 8);
    float4 a = s[0], c = s[1];
    ushort8v v;
    v[0] = f2bf(a.x); v[1] = f2bf(a.y); v[2] = f2bf(a.z); v[3] = f2bf(a.w);
    v[4] = f2bf(c.x); v[5] = f2bf(c.y); v[6] = f2bf(c.z); v[7] = f2bf(c.w);
    *reinterpret_cast<ushort8v*>(Web + i * 8) = v;
    return;
  }
  __shared__ int lhist[16];
  if (tid < 16) lhist[tid] = 0;
  __syncthreads();
  int w = tid >> 6, lane = tid & 63;
  int tok0 = b * 32 + w * 8;

  for (int t = 0; t < 8; ++t) {
    int tok = tok0 + t;
    const float* xr = x + (size_t)tok * KDIM + lane * 16;
    float acc[NEXP] = {};
    ushort8v xv0, xv1;
#pragma unroll
    for (int j4 = 0; j4 < 4; ++j4) {
      float4 xv = *reinterpret_cast<const float4*>(xr + j4 * 4);
      float xs[4] = {xv.x, xv.y, xv.z, xv.w};
#pragma unroll
      for (int jj = 0; jj < 4; ++jj) {
        int k = lane * 16 + j4 * 4 + jj;
        const float4* wr = reinterpret_cast<const float4*>(Wg + k * NEXP);
        float4 w0 = wr[0], w1 = wr[1];
        float xf = xs[jj];
        acc[0] += xf * w0.x; acc[1] += xf * w0.y;
        acc[2] += xf * w0.z; acc[3] += xf * w0.w;
        acc[4] += xf * w1.x; acc[5] += xf * w1.y;
        acc[6] += xf * w1.z; acc[7] += xf * w1.w;
        int li = j4 * 4 + jj;
        unsigned short bv = f2bf(xf);
        if (li < 8) xv0[li] = bv; else xv1[li - 8] = bv;
      }
    }
    unsigned short* xrow = xb + (size_t)tok * KDIM + lane * 16;
    *reinterpret_cast<ushort8v*>(xrow) = xv0;
    *reinterpret_cast<ushort8v*>(xrow + 8) = xv1;
#pragma unroll
    for (int e = 0; e < NEXP; ++e) {
      acc[e] += __shfl_xor(acc[e], 1, 64);
      acc[e] += __shfl_xor(acc[e], 2, 64);
      acc[e] += __shfl_xor(acc[e], 4, 64);
      acc[e] += __shfl_xor(acc[e], 8, 64);
      acc[e] += __shfl_xor(acc[e], 16, 64);
      acc[e] += __shfl_xor(acc[e], 32, 64);
    }
    if (lane == 0) {
      float lg[NEXP];
#pragma unroll
      for (int e = 0; e < NEXP; ++e) lg[e] = acc[e] + bg[e];
      int e0 = 0;
#pragma unroll
      for (int e = 1; e < NEXP; ++e) if (lg[e] > lg[e0]) e0 = e;
      int e1 = -1;
#pragma unroll
      for (int e = 0; e < NEXP; ++e) {
        if (e == e0) continue;
        if (e1 < 0 || lg[e] > lg[e1]) e1 = e;
      }
      float tv = expf(lg[e1] - lg[e0]);
      float w0 = 1.0f / (1.0f + tv);
      float w1 = tv * w0;
      epacked[tok] = e0 | (e1 << 8);
      wpair[tok] = make_float2(w0, w1);
      atomicAdd(&lhist[e0], 1);
      atomicAdd(&lhist[8 + e1], 1);
    }
  }
  __syncthreads();
  if (tid < 16) hist[b * 16 + tid] = lhist[tid];
}

// scatter: per-block exclusive prefix over histograms -> routed lists.
__global__ __launch_bounds__(256) void scatter_kernel(
    const int* __restrict__ hist, const int* __restrict__ epacked,
    const float2* __restrict__ wpair, int* __restrict__ counts,
    int* __restrict__ lists, float* __restrict__ wlists) {
  __shared__ int partial[16][17];
  __shared__ int base[16];
  __shared__ int cnt2[16];
  int tid = threadIdx.x;
  int b = blockIdx.x;
  int bin = tid & 15, grp = tid >> 4;
  int s = 0;
  for (int i = 0; i < 16; ++i) {
    int bb = grp * 16 + i;
    if (bb < b) s += hist[bb * 16 + bin];
  }
  partial[grp][bin] = s;
  if (tid < 16) cnt2[tid] = 0;
  __syncthreads();
  if (tid < 16) {
    int s2 = 0;
#pragma unroll
    for (int g = 0; g < 16; ++g) s2 += partial[g][tid];
    base[tid] = s2;
  }
  __syncthreads();
  if (tid < 64) {
    int tok = b * 32 + (tid >> 1);
    int slot = tid & 1;
    int ep = epacked[tok];
    int e = slot ? ((ep >> 8) & 255) : (ep & 255);
    float2 wp = wpair[tok];
    float wv = slot ? wp.y : wp.x;
    int bn = slot * 8 + e;
    int pos = base[bn] + atomicAdd(&cnt2[bn], 1);
    lists[bn * TOKENS + pos] = tok;
    wlists[bn * TOKENS + pos] = wv;
  }
  if (b == 255) {
    __syncthreads();
    if (tid < 16) counts[tid] = base[tid] + cnt2[tid];
  }
}

// 256x256xBK64 grouped GEMM, 256 THREADS / 4 waves (2Mx2N, wave out 128x128).
// Why 256 threads: regsPerBlock=131072 is a HARD per-block budget ->
// regs/thread <= 131072/threads. 512-thr capped at 256 (r5/r8/r10: acc alone
// ate it -> 500MB scratch). 256-thr gets 512/thread: acc[8][8]=256 + frags
// fits. LDS 128KB -> 1 block/CU, so no occupancy pressure on the allocator.
// Counted-vmcnt 2-deep pipeline; r4-proven atomic epilogue (out pre-zeroed).
__global__ __launch_bounds__(256) void moe_gemm_big(
    const unsigned short* __restrict__ xb, const unsigned short* __restrict__ Web,
    const float* __restrict__ be, const int* __restrict__ counts,
    const int* __restrict__ lists, const float* __restrict__ wlists,
    float* __restrict__ out) {
  int bz = blockIdx.z;           // slot*8 + expert
  int e = bz & 7;
  int cnt = counts[bz];
  int mbase = blockIdx.y * 256;  // 8 M-tiles -> 2048-token capacity
  if (mbase >= cnt) return;
  int nbase = blockIdx.x * 256;  // 4 N-tiles
  const int* lst = lists + bz * TOKENS;
  const float* wl = wlists + bz * TOKENS;

  // [2 bufs][256 rows][64 cols] bf16; stored 16B-chunk cs at row r = logical cs^(r&7)
  __shared__ alignas(128) unsigned short lA[2][256 * 64];  // 64 KiB
  __shared__ alignas(128) unsigned short lB[2][256 * 64];  // 64 KiB

  int tid = threadIdx.x;         // 0..255
  int lane = tid & 63;
  int w = tid >> 6;              // wave 0..3
  int wm = w >> 1, wn = w & 1;   // 2M x 2N; wave output 128x128
  int lm = lane & 15, lk = lane >> 4;

  // Staging: chunk L = j*256 + tid, j=0..7 (2048 chunks = 256 rows x 8).
  // row r = 32j + (tid>>3); stored chunk cs = tid&7; source logical chunk
  // c = cs ^ (r&7) = (tid&7) ^ ((tid>>3)&7)  [j-independent since 32j%8==0].
  int rsub = tid >> 3;                       // row within 32-row stripe
  int c = (tid & 7) ^ (rsub & 7);            // pre-swizzled source chunk (rule 21)
  const unsigned short* aga[8];
#pragma unroll
  for (int j = 0; j < 8; ++j) {
    int gr = mbase + j * 32 + rsub;
    if (gr >= cnt) gr = cnt - 1;
    aga[j] = xb + (size_t)lst[gr] * KDIM + c * 8;
  }
  const unsigned short* bga =
      Web + (size_t)e * (NDIM * KDIM) + (size_t)(nbase + rsub) * KDIM + c * 8;

#define STAGE(buf, kt)                                                          \
  {                                                                             \
    _Pragma("unroll") for (int j = 0; j < 8; ++j) {                             \
      gload_lds16(aga[j] + (kt) * 64, (char*)lA[buf] + j * 4096 + w * 1024);    \
      gload_lds16(bga + j * (32 * KDIM) + (kt) * 64,                            \
                  (char*)lB[buf] + j * 4096 + w * 1024);                        \
    }                                                                           \
  }

  f32x4 acc[8][8] = {};

  // COMPUTE: plain C++ ds_reads (compiler inserts fine-grained lgkmcnt).
#define COMPUTE(buf)                                                            \
  {                                                                             \
    _Pragma("unroll") for (int ks = 0; ks < 2; ++ks) {                          \
      short8v bfv[8];                                                           \
      _Pragma("unroll") for (int nj = 0; nj < 8; ++nj) {                        \
        int row = wn * 128 + nj * 16 + lm;                                      \
        int cs = (ks * 4 + lk) ^ (row & 7);                                     \
        bfv[nj] = *reinterpret_cast<const short8v*>(&lB[buf][row * 64 + cs * 8]); \
      }                                                                         \
      _Pragma("unroll") for (int mi = 0; mi < 8; ++mi) {                        \
        int row = wm * 128 + mi * 16 + lm;                                      \
        int cs = (ks * 4 + lk) ^ (row & 7);                                     \
        short8v af = *reinterpret_cast<const short8v*>(&lA[buf][row * 64 + cs * 8]); \
        _Pragma("unroll") for (int nj = 0; nj < 8; ++nj)                        \
          acc[mi][nj] = __builtin_amdgcn_mfma_f32_16x16x32_bf16(                \
              af, bfv[nj], acc[mi][nj], 0, 0, 0);                               \
      }                                                                         \
    }                                                                           \
  }

  // prologue: 2 K-tiles in flight (16 loads/thread each)
  STAGE(0, 0);
  STAGE(1, 1);
  for (int kt = 0; kt < 15; ++kt) {
    // wait only for the OLDER tile's 16 loads; newer tile's 16 stay in flight
    asm volatile("s_waitcnt vmcnt(16)" ::: "memory");
    asm volatile("s_barrier" ::: "memory");
    if ((kt & 1) == 0) COMPUTE(0) else COMPUTE(1);
    asm volatile("s_waitcnt lgkmcnt(0)" ::: "memory");  // all my ds_reads sampled
    asm volatile("s_barrier" ::: "memory");             // all waves done reading
    if (kt < 14) STAGE(kt & 1, kt + 2);
  }
  asm volatile("s_waitcnt vmcnt(0)" ::: "memory");
  asm volatile("s_barrier" ::: "memory");
  COMPUTE(1);
#undef STAGE
#undef COMPUTE

  // epilogue: C/D mapping col=lane&15, row=(lane>>4)*4+reg  [m89/m91]
  float bev[8];
#pragma unroll
  for (int nj = 0; nj < 8; ++nj)
    bev[nj] = be[e * NDIM + nbase + wn * 128 + nj * 16 + lm];
#pragma unroll
  for (int mi = 0; mi < 8; ++mi) {
#pragma unroll
    for (int r = 0; r < 4; ++r) {
      int grow = mbase + wm * 128 + mi * 16 + lk * 4 + r;
      if (grow >= cnt) continue;
      int tokn = lst[grow];
      float wgt = wl[grow];
      float* orow = out + (size_t)tokn * NDIM + nbase + wn * 128 + lm;
#pragma unroll
      for (int nj = 0; nj < 8; ++nj)
        unsafeAtomicAdd(&orow[nj * 16], wgt * (acc[mi][nj][r] + bev[nj]));
    }
  }
}

// ============================ DEEP FALLBACK (round-1) ============================

__global__ __launch_bounds__(256) void gate_kernel(
    const float* __restrict__ x, const float* __restrict__ Wg,
    const float* __restrict__ bg, int* __restrict__ counts,
    int* __restrict__ lists, float* __restrict__ wlists) {
  int gtid = blockIdx.x * blockDim.x + threadIdx.x;
  int tok = gtid >> 6;
  int lane = threadIdx.x & 63;
  if (tok >= TOKENS) return;
  const float* xr = x + (size_t)tok * KDIM + lane * 16;
  float acc[NEXP] = {};
#pragma unroll
  for (int j4 = 0; j4 < 4; ++j4) {
    float4 xv = *reinterpret_cast<const float4*>(xr + j4 * 4);
    float xs[4] = {xv.x, xv.y, xv.z, xv.w};
#pragma unroll
    for (int jj = 0; jj < 4; ++jj) {
      int k = lane * 16 + j4 * 4 + jj;
      const float4* wr = reinterpret_cast<const float4*>(Wg + k * NEXP);
      float4 w0 = wr[0], w1 = wr[1];
      float xv1 = xs[jj];
      acc[0] += xv1 * w0.x; acc[1] += xv1 * w0.y;
      acc[2] += xv1 * w0.z; acc[3] += xv1 * w0.w;
      acc[4] += xv1 * w1.x; acc[5] += xv1 * w1.y;
      acc[6] += xv1 * w1.z; acc[7] += xv1 * w1.w;
    }
  }
#pragma unroll
  for (int e = 0; e < NEXP; ++e) {
    acc[e] += __shfl_xor(acc[e], 1, 64);
    acc[e] += __shfl_xor(acc[e], 2, 64);
    acc[e] += __shfl_xor(acc[e], 4, 64);
    acc[e] += __shfl_xor(acc[e], 8, 64);
    acc[e] += __shfl_xor(acc[e], 16, 64);
    acc[e] += __shfl_xor(acc[e], 32, 64);
  }
  if (lane == 0) {
    float lg[NEXP];
#pragma unroll
    for (int e = 0; e < NEXP; ++e) lg[e] = acc[e] + bg[e];
    int e0 = 0;
#pragma unroll
    for (int e = 1; e < NEXP; ++e) if (lg[e] > lg[e0]) e0 = e;
    int e1 = -1;
#pragma unroll
    for (int e = 0; e < NEXP; ++e) {
      if (e == e0) continue;
      if (e1 < 0 || lg[e] > lg[e1]) e1 = e;
    }
    float t = expf(lg[e1] - lg[e0]);
    float w0 = 1.0f / (1.0f + t);
    float w1 = t * w0;
    int p0 = atomicAdd(&counts[e0], 1);
    lists[e0 * TOKENS + p0] = tok;
    wlists[e0 * TOKENS + p0] = w0;
    int p1 = atomicAdd(&counts[NEXP + e1], 1);
    lists[(NEXP + e1) * TOKENS + p1] = tok;
    wlists[(NEXP + e1) * TOKENS + p1] = w1;
  }
}

template <int ACCUM>
__global__ __launch_bounds__(256) void moe_gemm(
    const float* __restrict__ x, const float* __restrict__ We,
    const float* __restrict__ be, const int* __restrict__ counts,
    const int* __restrict__ lists, const float* __restrict__ wlists,
    float* __restrict__ out, int slot) {
  int e = blockIdx.z;
  int cnt = counts[slot * NEXP + e];
  int mbase = blockIdx.y * 128;
  if (mbase >= cnt) return;
  int nbase = blockIdx.x * 128;
  const int* lst = lists + (slot * NEXP + e) * TOKENS;
  const float* wl = wlists + (slot * NEXP + e) * TOKENS;
  __shared__ ushort8v lA[1024];
  __shared__ ushort8v lB[1024];
  int tid = threadIdx.x;
  int lane = tid & 63;
  int w = tid >> 6;
  int wm = w >> 1, wn = w & 1;
  const float* aptr[4];
  const float* bptr[4];
  int sw[4];
#pragma unroll
  for (int i = 0; i < 4; ++i) {
    int c = i * 256 + tid;
    int r = c >> 3, cc = c & 7;
    int gr = mbase + r;
    if (gr >= cnt) gr = cnt - 1;
    int tokn = lst[gr];
    aptr[i] = x + (size_t)tokn * KDIM + cc * 8;
    bptr[i] = We + (size_t)e * (NDIM * KDIM) + (size_t)(nbase + r) * KDIM + cc * 8;
    sw[i] = r * 8 + (cc ^ (r & 7));
  }
  f32x4 acc[4][4] = {};
  int lm = lane & 15, lk = lane >> 4;
  for (int kt = 0; kt < KDIM / 64; ++kt) {
    __syncthreads();
#pragma unroll
    for (int i = 0; i < 4; ++i) {
      float4 f0 = *reinterpret_cast<const float4*>(aptr[i] + kt * 64);
      float4 f1 = *reinterpret_cast<const float4*>(aptr[i] + kt * 64 + 4);
      ushort8v v;
      v[0] = f2bf(f0.x); v[1] = f2bf(f0.y); v[2] = f2bf(f0.z); v[3] = f2bf(f0.w);
      v[4] = f2bf(f1.x); v[5] = f2bf(f1.y); v[6] = f2bf(f1.z); v[7] = f2bf(f1.w);
      lA[sw[i]] = v;
      float4 g0 = *reinterpret_cast<const float4*>(bptr[i] + kt * 64);
      float4 g1 = *reinterpret_cast<const float4*>(bptr[i] + kt * 64 + 4);
      ushort8v u;
      u[0] = f2bf(g0.x); u[1] = f2bf(g0.y); u[2] = f2bf(g0.z); u[3] = f2bf(g0.w);
      u[4] = f2bf(g1.x); u[5] = f2bf(g1.y); u[6] = f2bf(g1.z); u[7] = f2bf(g1.w);
      lB[sw[i]] = u;
    }
    __syncthreads();
#pragma unroll
    for (int ks = 0; ks < 2; ++ks) {
      short8v af[4], bfv[4];
#pragma unroll
      for (int mi = 0; mi < 4; ++mi) {
        int row = wm * 64 + mi * 16 + lm;
        int cidx = (ks * 4 + lk) ^ (row & 7);
        af[mi] = *reinterpret_cast<const short8v*>(&lA[row * 8 + cidx]);
      }
#pragma unroll
      for (int nj = 0; nj < 4; ++nj) {
        int row = wn * 64 + nj * 16 + lm;
        int cidx = (ks * 4 + lk) ^ (row & 7);
        bfv[nj] = *reinterpret_cast<const short8v*>(&lB[row * 8 + cidx]);
      }
#pragma unroll
      for (int mi = 0; mi < 4; ++mi)
#pragma unroll
        for (int nj = 0; nj < 4; ++nj)
          acc[mi][nj] = __builtin_amdgcn_mfma_f32_16x16x32_bf16(
              af[mi], bfv[nj], acc[mi][nj], 0, 0, 0);
    }
  }
  float bev[4];
#pragma unroll
  for (int nj = 0; nj < 4; ++nj)
    bev[nj] = be[e * NDIM + nbase + wn * 64 + nj * 16 + lm];
#pragma unroll
  for (int mi = 0; mi < 4; ++mi) {
#pragma unroll
    for (int r = 0; r < 4; ++r) {
      int grow = mbase + wm * 64 + mi * 16 + lk * 4 + r;
      if (grow >= cnt) continue;
      int tokn = lst[grow];
      float wgt = wl[grow];
      float* orow = out + (size_t)tokn * NDIM + nbase + wn * 64 + lm;
#pragma unroll
      for (int nj = 0; nj < 4; ++nj) {
        float val = wgt * (acc[mi][nj][r] + bev[nj]);
        if (ACCUM) orow[nj * 16] += val;
        else       orow[nj * 16] = val;
      }
    }
  }
}

// ============================ HOST ============================

extern "C" void kernel_launch(void* const* d_in, const int* in_sizes, int n_in,
                              void* d_out, int out_size, void* d_ws, size_t ws_size,
                              hipStream_t stream) {
  const float* x  = (const float*)d_in[0];
  const float* Wg = (const float*)d_in[1];
  const float* bg = (const float*)d_in[2];
  const float* We = (const float*)d_in[3];
  const float* be = (const float*)d_in[4];
  float* out = (float*)d_out;

  char* p = (char*)d_ws;
  int*   counts = (int*)p;                 p += 256;
  int*   lists  = (int*)p;                 p += (size_t)16 * TOKENS * 4;  // 512 KB
  float* wlists = (float*)p;               p += (size_t)16 * TOKENS * 4;  // 512 KB
  int*   epacked = (int*)p;                p += (size_t)TOKENS * 4;       // 32 KB
  float2* wpair  = (float2*)p;             p += (size_t)TOKENS * 8;       // 64 KB
  int*   hist    = (int*)p;                p += 256 * 16 * 4;             // 16 KB
  unsigned short* xbuf = (unsigned short*)p; p += (size_t)TOKENS * KDIM * 2;       // 16 MB
  unsigned short* Webf = (unsigned short*)p; p += (size_t)NEXP * NDIM * KDIM * 2;  // 16 MB
  size_t need = (size_t)(p - (char*)d_ws);

  if (ws_size >= need) {
    gate_conv_kernel<<<5376, 256, 0, stream>>>(
        x, Wg, bg, We, xbuf, Webf, epacked, wpair, hist, out);
    scatter_kernel<<<256, 256, 0, stream>>>(hist, epacked, wpair, counts, lists, wlists);
    dim3 grid(4, 8, 16);  // 4 N-tiles x 8 M-tiles (2048 cap) x 16 groups
    moe_gemm_big<<<grid, 256, 0, stream>>>(xbuf, Webf, be, counts, lists, wlists, out);
  } else {
    dim3 grid(NDIM / 128, TOKENS / 128, NEXP);
    hipMemsetAsync(d_ws, 0, 64, stream);
    gate_kernel<<<TOKENS / 4, 256, 0, stream>>>(x, Wg, bg, counts, lists, wlists);
    moe_gemm<0><<<grid, 256, 0, stream>>>(x, We, be, counts, lists, wlists, out, 0);
    moe_gemm<1><<<grid, 256, 0, stream>>>(x, We, be, counts, lists, wlists, out, 1);
  }
}

// Round 12
// 265.084 us; speedup vs baseline: 1.7648x; 1.2474x over previous
//
#include <hip/hip_runtime.h>
#include <hip/hip_bf16.h>

#define TOKENS 8192
#define KDIM 1024
#define NDIM 1024
#define NEXP 8

typedef __attribute__((ext_vector_type(8))) short short8v;
typedef __attribute__((ext_vector_type(8))) unsigned short ushort8v;
typedef __attribute__((ext_vector_type(4))) float f32x4;

__device__ inline unsigned short f2bf(float f) {
  unsigned int u = __float_as_uint(f);
  u += 0x7fffu + ((u >> 16) & 1u);
  return (unsigned short)(u >> 16);
}

__device__ inline void gload_lds16(const void* g, void* l) {
  __builtin_amdgcn_global_load_lds(
      (const __attribute__((address_space(1))) unsigned int*)g,
      (__attribute__((address_space(3))) unsigned int*)l, 16, 0, 0);
}

// ============================ FAST PATH ============================

// Fused: [0,256) gating + x->bf16; [256,4352) We->bf16; [4352,5376) zero out.
__global__ __launch_bounds__(256) void gate_conv_kernel(
    const float* __restrict__ x, const float* __restrict__ Wg,
    const float* __restrict__ bg, const float* __restrict__ We,
    unsigned short* __restrict__ xb, unsigned short* __restrict__ Web,
    int* __restrict__ epacked, float2* __restrict__ wpair,
    int* __restrict__ hist, float* __restrict__ out) {
  int b = blockIdx.x;
  int tid = threadIdx.x;
  if (b >= 4352) {
    float4* o = reinterpret_cast<float4*>(out) + (size_t)(b - 4352) * 2048 + tid;
    float4 z = make_float4(0.f, 0.f, 0.f, 0.f);
#pragma unroll
    for (int i = 0; i < 8; ++i) o[i * 256] = z;
    return;
  }
  if (b >= 256) {
    size_t i = (size_t)(b - 256) * 256 + tid;
    const float4* s = reinterpret_cast<const float4*>(We + i * 8);
    float4 a = s[0], c = s[1];
    ushort8v v;
    v[0] = f2bf(a.x); v[1] = f2bf(a.y); v[2] = f2bf(a.z); v[3] = f2bf(a.w);
    v[4] = f2bf(c.x); v[5] = f2bf(c.y); v[6] = f2bf(c.z); v[7] = f2bf(c.w);
    *reinterpret_cast<ushort8v*>(Web + i * 8) = v;
    return;
  }
  __shared__ int lhist[16];
  if (tid < 16) lhist[tid] = 0;
  __syncthreads();
  int w = tid >> 6, lane = tid & 63;
  int tok0 = b * 32 + w * 8;

  for (int t = 0; t < 8; ++t) {
    int tok = tok0 + t;
    const float* xr = x + (size_t)tok * KDIM + lane * 16;
    float acc[NEXP] = {};
    ushort8v xv0, xv1;
#pragma unroll
    for (int j4 = 0; j4 < 4; ++j4) {
      float4 xv = *reinterpret_cast<const float4*>(xr + j4 * 4);
      float xs[4] = {xv.x, xv.y, xv.z, xv.w};
#pragma unroll
      for (int jj = 0; jj < 4; ++jj) {
        int k = lane * 16 + j4 * 4 + jj;
        const float4* wr = reinterpret_cast<const float4*>(Wg + k * NEXP);
        float4 w0 = wr[0], w1 = wr[1];
        float xf = xs[jj];
        acc[0] += xf * w0.x; acc[1] += xf * w0.y;
        acc[2] += xf * w0.z; acc[3] += xf * w0.w;
        acc[4] += xf * w1.x; acc[5] += xf * w1.y;
        acc[6] += xf * w1.z; acc[7] += xf * w1.w;
        int li = j4 * 4 + jj;
        unsigned short bv = f2bf(xf);
        if (li < 8) xv0[li] = bv; else xv1[li - 8] = bv;
      }
    }
    unsigned short* xrow = xb + (size_t)tok * KDIM + lane * 16;
    *reinterpret_cast<ushort8v*>(xrow) = xv0;
    *reinterpret_cast<ushort8v*>(xrow + 8) = xv1;
#pragma unroll
    for (int e = 0; e < NEXP; ++e) {
      acc[e] += __shfl_xor(acc[e], 1, 64);
      acc[e] += __shfl_xor(acc[e], 2, 64);
      acc[e] += __shfl_xor(acc[e], 4, 64);
      acc[e] += __shfl_xor(acc[e], 8, 64);
      acc[e] += __shfl_xor(acc[e], 16, 64);
      acc[e] += __shfl_xor(acc[e], 32, 64);
    }
    if (lane == 0) {
      float lg[NEXP];
#pragma unroll
      for (int e = 0; e < NEXP; ++e) lg[e] = acc[e] + bg[e];
      int e0 = 0;
#pragma unroll
      for (int e = 1; e < NEXP; ++e) if (lg[e] > lg[e0]) e0 = e;
      int e1 = -1;
#pragma unroll
      for (int e = 0; e < NEXP; ++e) {
        if (e == e0) continue;
        if (e1 < 0 || lg[e] > lg[e1]) e1 = e;
      }
      float tv = expf(lg[e1] - lg[e0]);
      float w0 = 1.0f / (1.0f + tv);
      float w1 = tv * w0;
      epacked[tok] = e0 | (e1 << 8);
      wpair[tok] = make_float2(w0, w1);
      atomicAdd(&lhist[e0], 1);
      atomicAdd(&lhist[8 + e1], 1);
    }
  }
  __syncthreads();
  if (tid < 16) hist[b * 16 + tid] = lhist[tid];
}

// scatter: per-block exclusive prefix over histograms -> routed lists.
__global__ __launch_bounds__(256) void scatter_kernel(
    const int* __restrict__ hist, const int* __restrict__ epacked,
    const float2* __restrict__ wpair, int* __restrict__ counts,
    int* __restrict__ lists, float* __restrict__ wlists) {
  __shared__ int partial[16][17];
  __shared__ int base[16];
  __shared__ int cnt2[16];
  int tid = threadIdx.x;
  int b = blockIdx.x;
  int bin = tid & 15, grp = tid >> 4;
  int s = 0;
  for (int i = 0; i < 16; ++i) {
    int bb = grp * 16 + i;
    if (bb < b) s += hist[bb * 16 + bin];
  }
  partial[grp][bin] = s;
  if (tid < 16) cnt2[tid] = 0;
  __syncthreads();
  if (tid < 16) {
    int s2 = 0;
#pragma unroll
    for (int g = 0; g < 16; ++g) s2 += partial[g][tid];
    base[tid] = s2;
  }
  __syncthreads();
  if (tid < 64) {
    int tok = b * 32 + (tid >> 1);
    int slot = tid & 1;
    int ep = epacked[tok];
    int e = slot ? ((ep >> 8) & 255) : (ep & 255);
    float2 wp = wpair[tok];
    float wv = slot ? wp.y : wp.x;
    int bn = slot * 8 + e;
    int pos = base[bn] + atomicAdd(&cnt2[bn], 1);
    lists[bn * TOKENS + pos] = tok;
    wlists[bn * TOKENS + pos] = wv;
  }
  if (b == 255) {
    __syncthreads();
    if (tid < 16) counts[tid] = base[tid] + cnt2[tid];
  }
}

// 256x256 tile, K-SPLIT x2 (each block: K=512, 8 K-tiles of 64).
// 256 threads / 4 waves (2Mx2N, wave out 128x128, acc[8][8] -> AGPR; r11
// proved this register shape compiles spill-free: VGPR=256, no scratch).
// SINGLE-buffer LDS 64 KB -> 2 blocks/CU -> 2 waves/SIMD (r11's 128KB dbuf
// gave 1 wave/SIMD = zero latency hiding = 330us). Serial 2-barrier loop
// (r2/r4-proven; __syncthreads drains vmcnt before s_barrier).
// K-split doubles active blocks (512 = 2/CU) so the 2 LDS slots actually fill.
// Atomic epilogue onto pre-zeroed out; bias added only by khalf==0.
__global__ __launch_bounds__(256) void moe_gemm_big(
    const unsigned short* __restrict__ xb, const unsigned short* __restrict__ Web,
    const float* __restrict__ be, const int* __restrict__ counts,
    const int* __restrict__ lists, const float* __restrict__ wlists,
    float* __restrict__ out) {
  int bz = blockIdx.z;           // 0..31: group = bz&15 (slot*8+e), khalf = bz>>4
  int grp = bz & 15;
  int khalf = bz >> 4;
  int e = grp & 7;
  int cnt = counts[grp];
  int mbase = blockIdx.y * 256;  // 8 M-tiles -> 2048-token capacity
  if (mbase >= cnt) return;
  int nbase = blockIdx.x * 256;  // 4 N-tiles
  const int* lst = lists + grp * TOKENS;
  const float* wl = wlists + grp * TOKENS;

  // single buffer [256 rows][64 cols] bf16; stored chunk cs at row r = logical cs^(r&7)
  __shared__ alignas(128) unsigned short lA[256 * 64];  // 32 KiB
  __shared__ alignas(128) unsigned short lB[256 * 64];  // 32 KiB

  int tid = threadIdx.x;         // 0..255
  int lane = tid & 63;
  int w = tid >> 6;              // wave 0..3
  int wm = w >> 1, wn = w & 1;   // 2M x 2N; wave output 128x128
  int lm = lane & 15, lk = lane >> 4;

  // Staging: chunk L = j*256 + tid, j=0..7 (2048 chunks = 256 rows x 8).
  // row r = 32j + (tid>>3); stored cs = tid&7; source logical chunk
  // c = (tid&7) ^ (r&7) = (tid&7) ^ ((tid>>3)&7)   [j-independent: 32j%8==0]
  int rsub = tid >> 3;
  int c = (tid & 7) ^ (rsub & 7);            // pre-swizzled source (rule 21)
  int kofs = khalf * 512;                    // this block's K-half
  const unsigned short* aga[8];
#pragma unroll
  for (int j = 0; j < 8; ++j) {
    int gr = mbase + j * 32 + rsub;
    if (gr >= cnt) gr = cnt - 1;
    aga[j] = xb + (size_t)lst[gr] * KDIM + kofs + c * 8;
  }
  const unsigned short* bga =
      Web + (size_t)e * (NDIM * KDIM) + (size_t)(nbase + rsub) * KDIM + kofs + c * 8;

#define STAGE(kt)                                                            \
  {                                                                          \
    _Pragma("unroll") for (int j = 0; j < 8; ++j) {                          \
      gload_lds16(aga[j] + (kt) * 64, (char*)lA + j * 4096 + w * 1024);      \
      gload_lds16(bga + j * (32 * KDIM) + (kt) * 64,                         \
                  (char*)lB + j * 4096 + w * 1024);                          \
    }                                                                        \
  }

  f32x4 acc[8][8] = {};

#define COMPUTE                                                              \
  {                                                                          \
    _Pragma("unroll") for (int ks = 0; ks < 2; ++ks) {                       \
      short8v bfv[8];                                                        \
      _Pragma("unroll") for (int nj = 0; nj < 8; ++nj) {                     \
        int row = wn * 128 + nj * 16 + lm;                                   \
        int cs = (ks * 4 + lk) ^ (row & 7);                                  \
        bfv[nj] = *reinterpret_cast<const short8v*>(&lB[row * 64 + cs * 8]); \
      }                                                                      \
      _Pragma("unroll") for (int mi = 0; mi < 8; ++mi) {                     \
        int row = wm * 128 + mi * 16 + lm;                                   \
        int cs = (ks * 4 + lk) ^ (row & 7);                                  \
        short8v af = *reinterpret_cast<const short8v*>(&lA[row * 64 + cs * 8]); \
        _Pragma("unroll") for (int nj = 0; nj < 8; ++nj)                     \
          acc[mi][nj] = __builtin_amdgcn_mfma_f32_16x16x32_bf16(             \
              af, bfv[nj], acc[mi][nj], 0, 0, 0);                            \
      }                                                                      \
    }                                                                        \
  }

  for (int kt = 0; kt < 8; ++kt) {
    __syncthreads();   // previous COMPUTE's ds_reads done before overwrite
    STAGE(kt);
    __syncthreads();   // compiler drains vmcnt(0) before s_barrier -> tile ready
    COMPUTE;
  }
#undef STAGE
#undef COMPUTE

  // epilogue: C/D mapping col=lane&15, row=(lane>>4)*4+reg  [m89/m91]
  float bev[8];
#pragma unroll
  for (int nj = 0; nj < 8; ++nj)
    bev[nj] = khalf ? 0.f : be[e * NDIM + nbase + wn * 128 + nj * 16 + lm];
#pragma unroll
  for (int mi = 0; mi < 8; ++mi) {
#pragma unroll
    for (int r = 0; r < 4; ++r) {
      int grow = mbase + wm * 128 + mi * 16 + lk * 4 + r;
      if (grow >= cnt) continue;
      int tokn = lst[grow];
      float wgt = wl[grow];
      float* orow = out + (size_t)tokn * NDIM + nbase + wn * 128 + lm;
#pragma unroll
      for (int nj = 0; nj < 8; ++nj)
        unsafeAtomicAdd(&orow[nj * 16], wgt * (acc[mi][nj][r] + bev[nj]));
    }
  }
}

// ============================ DEEP FALLBACK (round-1) ============================

__global__ __launch_bounds__(256) void gate_kernel(
    const float* __restrict__ x, const float* __restrict__ Wg,
    const float* __restrict__ bg, int* __restrict__ counts,
    int* __restrict__ lists, float* __restrict__ wlists) {
  int gtid = blockIdx.x * blockDim.x + threadIdx.x;
  int tok = gtid >> 6;
  int lane = threadIdx.x & 63;
  if (tok >= TOKENS) return;
  const float* xr = x + (size_t)tok * KDIM + lane * 16;
  float acc[NEXP] = {};
#pragma unroll
  for (int j4 = 0; j4 < 4; ++j4) {
    float4 xv = *reinterpret_cast<const float4*>(xr + j4 * 4);
    float xs[4] = {xv.x, xv.y, xv.z, xv.w};
#pragma unroll
    for (int jj = 0; jj < 4; ++jj) {
      int k = lane * 16 + j4 * 4 + jj;
      const float4* wr = reinterpret_cast<const float4*>(Wg + k * NEXP);
      float4 w0 = wr[0], w1 = wr[1];
      float xv1 = xs[jj];
      acc[0] += xv1 * w0.x; acc[1] += xv1 * w0.y;
      acc[2] += xv1 * w0.z; acc[3] += xv1 * w0.w;
      acc[4] += xv1 * w1.x; acc[5] += xv1 * w1.y;
      acc[6] += xv1 * w1.z; acc[7] += xv1 * w1.w;
    }
  }
#pragma unroll
  for (int e = 0; e < NEXP; ++e) {
    acc[e] += __shfl_xor(acc[e], 1, 64);
    acc[e] += __shfl_xor(acc[e], 2, 64);
    acc[e] += __shfl_xor(acc[e], 4, 64);
    acc[e] += __shfl_xor(acc[e], 8, 64);
    acc[e] += __shfl_xor(acc[e], 16, 64);
    acc[e] += __shfl_xor(acc[e], 32, 64);
  }
  if (lane == 0) {
    float lg[NEXP];
#pragma unroll
    for (int e = 0; e < NEXP; ++e) lg[e] = acc[e] + bg[e];
    int e0 = 0;
#pragma unroll
    for (int e = 1; e < NEXP; ++e) if (lg[e] > lg[e0]) e0 = e;
    int e1 = -1;
#pragma unroll
    for (int e = 0; e < NEXP; ++e) {
      if (e == e0) continue;
      if (e1 < 0 || lg[e] > lg[e1]) e1 = e;
    }
    float t = expf(lg[e1] - lg[e0]);
    float w0 = 1.0f / (1.0f + t);
    float w1 = t * w0;
    int p0 = atomicAdd(&counts[e0], 1);
    lists[e0 * TOKENS + p0] = tok;
    wlists[e0 * TOKENS + p0] = w0;
    int p1 = atomicAdd(&counts[NEXP + e1], 1);
    lists[(NEXP + e1) * TOKENS + p1] = tok;
    wlists[(NEXP + e1) * TOKENS + p1] = w1;
  }
}

template <int ACCUM>
__global__ __launch_bounds__(256) void moe_gemm(
    const float* __restrict__ x, const float* __restrict__ We,
    const float* __restrict__ be, const int* __restrict__ counts,
    const int* __restrict__ lists, const float* __restrict__ wlists,
    float* __restrict__ out, int slot) {
  int e = blockIdx.z;
  int cnt = counts[slot * NEXP + e];
  int mbase = blockIdx.y * 128;
  if (mbase >= cnt) return;
  int nbase = blockIdx.x * 128;
  const int* lst = lists + (slot * NEXP + e) * TOKENS;
  const float* wl = wlists + (slot * NEXP + e) * TOKENS;
  __shared__ ushort8v lA[1024];
  __shared__ ushort8v lB[1024];
  int tid = threadIdx.x;
  int lane = tid & 63;
  int w = tid >> 6;
  int wm = w >> 1, wn = w & 1;
  const float* aptr[4];
  const float* bptr[4];
  int sw[4];
#pragma unroll
  for (int i = 0; i < 4; ++i) {
    int c = i * 256 + tid;
    int r = c >> 3, cc = c & 7;
    int gr = mbase + r;
    if (gr >= cnt) gr = cnt - 1;
    int tokn = lst[gr];
    aptr[i] = x + (size_t)tokn * KDIM + cc * 8;
    bptr[i] = We + (size_t)e * (NDIM * KDIM) + (size_t)(nbase + r) * KDIM + cc * 8;
    sw[i] = r * 8 + (cc ^ (r & 7));
  }
  f32x4 acc[4][4] = {};
  int lm = lane & 15, lk = lane >> 4;
  for (int kt = 0; kt < KDIM / 64; ++kt) {
    __syncthreads();
#pragma unroll
    for (int i = 0; i < 4; ++i) {
      float4 f0 = *reinterpret_cast<const float4*>(aptr[i] + kt * 64);
      float4 f1 = *reinterpret_cast<const float4*>(aptr[i] + kt * 64 + 4);
      ushort8v v;
      v[0] = f2bf(f0.x); v[1] = f2bf(f0.y); v[2] = f2bf(f0.z); v[3] = f2bf(f0.w);
      v[4] = f2bf(f1.x); v[5] = f2bf(f1.y); v[6] = f2bf(f1.z); v[7] = f2bf(f1.w);
      lA[sw[i]] = v;
      float4 g0 = *reinterpret_cast<const float4*>(bptr[i] + kt * 64);
      float4 g1 = *reinterpret_cast<const float4*>(bptr[i] + kt * 64 + 4);
      ushort8v u;
      u[0] = f2bf(g0.x); u[1] = f2bf(g0.y); u[2] = f2bf(g0.z); u[3] = f2bf(g0.w);
      u[4] = f2bf(g1.x); u[5] = f2bf(g1.y); u[6] = f2bf(g1.z); u[7] = f2bf(g1.w);
      lB[sw[i]] = u;
    }
    __syncthreads();
#pragma unroll
    for (int ks = 0; ks < 2; ++ks) {
      short8v af[4], bfv[4];
#pragma unroll
      for (int mi = 0; mi < 4; ++mi) {
        int row = wm * 64 + mi * 16 + lm;
        int cidx = (ks * 4 + lk) ^ (row & 7);
        af[mi] = *reinterpret_cast<const short8v*>(&lA[row * 8 + cidx]);
      }
#pragma unroll
      for (int nj = 0; nj < 4; ++nj) {
        int row = wn * 64 + nj * 16 + lm;
        int cidx = (ks * 4 + lk) ^ (row & 7);
        bfv[nj] = *reinterpret_cast<const short8v*>(&lB[row * 8 + cidx]);
      }
#pragma unroll
      for (int mi = 0; mi < 4; ++mi)
#pragma unroll
        for (int nj = 0; nj < 4; ++nj)
          acc[mi][nj] = __builtin_amdgcn_mfma_f32_16x16x32_bf16(
              af[mi], bfv[nj], acc[mi][nj], 0, 0, 0);
    }
  }
  float bev[4];
#pragma unroll
  for (int nj = 0; nj < 4; ++nj)
    bev[nj] = be[e * NDIM + nbase + wn * 64 + nj * 16 + lm];
#pragma unroll
  for (int mi = 0; mi < 4; ++mi) {
#pragma unroll
    for (int r = 0; r < 4; ++r) {
      int grow = mbase + wm * 64 + mi * 16 + lk * 4 + r;
      if (grow >= cnt) continue;
      int tokn = lst[grow];
      float wgt = wl[grow];
      float* orow = out + (size_t)tokn * NDIM + nbase + wn * 64 + lm;
#pragma unroll
      for (int nj = 0; nj < 4; ++nj) {
        float val = wgt * (acc[mi][nj][r] + bev[nj]);
        if (ACCUM) orow[nj * 16] += val;
        else       orow[nj * 16] = val;
      }
    }
  }
}

// ============================ HOST ============================

extern "C" void kernel_launch(void* const* d_in, const int* in_sizes, int n_in,
                              void* d_out, int out_size, void* d_ws, size_t ws_size,
                              hipStream_t stream) {
  const float* x  = (const float*)d_in[0];
  const float* Wg = (const float*)d_in[1];
  const float* bg = (const float*)d_in[2];
  const float* We = (const float*)d_in[3];
  const float* be = (const float*)d_in[4];
  float* out = (float*)d_out;

  char* p = (char*)d_ws;
  int*   counts = (int*)p;                 p += 256;
  int*   lists  = (int*)p;                 p += (size_t)16 * TOKENS * 4;  // 512 KB
  float* wlists = (float*)p;               p += (size_t)16 * TOKENS * 4;  // 512 KB
  int*   epacked = (int*)p;                p += (size_t)TOKENS * 4;       // 32 KB
  float2* wpair  = (float2*)p;             p += (size_t)TOKENS * 8;       // 64 KB
  int*   hist    = (int*)p;                p += 256 * 16 * 4;             // 16 KB
  unsigned short* xbuf = (unsigned short*)p; p += (size_t)TOKENS * KDIM * 2;       // 16 MB
  unsigned short* Webf = (unsigned short*)p; p += (size_t)NEXP * NDIM * KDIM * 2;  // 16 MB
  size_t need = (size_t)(p - (char*)d_ws);

  if (ws_size >= need) {
    gate_conv_kernel<<<5376, 256, 0, stream>>>(
        x, Wg, bg, We, xbuf, Webf, epacked, wpair, hist, out);
    scatter_kernel<<<256, 256, 0, stream>>>(hist, epacked, wpair, counts, lists, wlists);
    dim3 grid(4, 8, 32);  // 4 N x 8 M (2048 cap) x (16 groups x 2 k-halves)
    moe_gemm_big<<<grid, 256, 0, stream>>>(xbuf, Webf, be, counts, lists, wlists, out);
  } else {
    dim3 grid(NDIM / 128, TOKENS / 128, NEXP);
    hipMemsetAsync(d_ws, 0, 64, stream);
    gate_kernel<<<TOKENS / 4, 256, 0, stream>>>(x, Wg, bg, counts, lists, wlists);
    moe_gemm<0><<<grid, 256, 0, stream>>>(x, We, be, counts, lists, wlists, out, 0);
    moe_gemm<1><<<grid, 256, 0, stream>>>(x, We, be, counts, lists, wlists, out, 1);
  }
}

// Round 13
// 138.822 us; speedup vs baseline: 3.3700x; 1.9095x over previous
//
#include <hip/hip_runtime.h>
#include <hip/hip_bf16.h>

#define TOKENS 8192
#define KDIM 1024
#define NDIM 1024
#define NEXP 8

typedef __attribute__((ext_vector_type(8))) short short8v;
typedef __attribute__((ext_vector_type(8))) unsigned short ushort8v;
typedef __attribute__((ext_vector_type(4))) float f32x4;

__device__ inline unsigned short f2bf(float f) {
  unsigned int u = __float_as_uint(f);
  u += 0x7fffu + ((u >> 16) & 1u);
  return (unsigned short)(u >> 16);
}

__device__ inline void gload_lds16(const void* g, void* l) {
  __builtin_amdgcn_global_load_lds(
      (const __attribute__((address_space(1))) unsigned int*)g,
      (__attribute__((address_space(3))) unsigned int*)l, 16, 0, 0);
}

// ============================ FAST PATH ============================

// Fused: [0,256) gating + x->bf16; [256,4352) We->bf16; [4352,5376) zero out.
__global__ __launch_bounds__(256) void gate_conv_kernel(
    const float* __restrict__ x, const float* __restrict__ Wg,
    const float* __restrict__ bg, const float* __restrict__ We,
    unsigned short* __restrict__ xb, unsigned short* __restrict__ Web,
    int* __restrict__ epacked, float2* __restrict__ wpair,
    int* __restrict__ hist, float* __restrict__ out) {
  int b = blockIdx.x;
  int tid = threadIdx.x;
  if (b >= 4352) {
    float4* o = reinterpret_cast<float4*>(out) + (size_t)(b - 4352) * 2048 + tid;
    float4 z = make_float4(0.f, 0.f, 0.f, 0.f);
#pragma unroll
    for (int i = 0; i < 8; ++i) o[i * 256] = z;
    return;
  }
  if (b >= 256) {
    size_t i = (size_t)(b - 256) * 256 + tid;
    const float4* s = reinterpret_cast<const float4*>(We + i * 8);
    float4 a = s[0], c = s[1];
    ushort8v v;
    v[0] = f2bf(a.x); v[1] = f2bf(a.y); v[2] = f2bf(a.z); v[3] = f2bf(a.w);
    v[4] = f2bf(c.x); v[5] = f2bf(c.y); v[6] = f2bf(c.z); v[7] = f2bf(c.w);
    *reinterpret_cast<ushort8v*>(Web + i * 8) = v;
    return;
  }
  __shared__ int lhist[16];
  if (tid < 16) lhist[tid] = 0;
  __syncthreads();
  int w = tid >> 6, lane = tid & 63;
  int tok0 = b * 32 + w * 8;

  for (int t = 0; t < 8; ++t) {
    int tok = tok0 + t;
    const float* xr = x + (size_t)tok * KDIM + lane * 16;
    float acc[NEXP] = {};
    ushort8v xv0, xv1;
#pragma unroll
    for (int j4 = 0; j4 < 4; ++j4) {
      float4 xv = *reinterpret_cast<const float4*>(xr + j4 * 4);
      float xs[4] = {xv.x, xv.y, xv.z, xv.w};
#pragma unroll
      for (int jj = 0; jj < 4; ++jj) {
        int k = lane * 16 + j4 * 4 + jj;
        const float4* wr = reinterpret_cast<const float4*>(Wg + k * NEXP);
        float4 w0 = wr[0], w1 = wr[1];
        float xf = xs[jj];
        acc[0] += xf * w0.x; acc[1] += xf * w0.y;
        acc[2] += xf * w0.z; acc[3] += xf * w0.w;
        acc[4] += xf * w1.x; acc[5] += xf * w1.y;
        acc[6] += xf * w1.z; acc[7] += xf * w1.w;
        int li = j4 * 4 + jj;
        unsigned short bv = f2bf(xf);
        if (li < 8) xv0[li] = bv; else xv1[li - 8] = bv;
      }
    }
    unsigned short* xrow = xb + (size_t)tok * KDIM + lane * 16;
    *reinterpret_cast<ushort8v*>(xrow) = xv0;
    *reinterpret_cast<ushort8v*>(xrow + 8) = xv1;
#pragma unroll
    for (int e = 0; e < NEXP; ++e) {
      acc[e] += __shfl_xor(acc[e], 1, 64);
      acc[e] += __shfl_xor(acc[e], 2, 64);
      acc[e] += __shfl_xor(acc[e], 4, 64);
      acc[e] += __shfl_xor(acc[e], 8, 64);
      acc[e] += __shfl_xor(acc[e], 16, 64);
      acc[e] += __shfl_xor(acc[e], 32, 64);
    }
    if (lane == 0) {
      float lg[NEXP];
#pragma unroll
      for (int e = 0; e < NEXP; ++e) lg[e] = acc[e] + bg[e];
      int e0 = 0;
#pragma unroll
      for (int e = 1; e < NEXP; ++e) if (lg[e] > lg[e0]) e0 = e;
      int e1 = -1;
#pragma unroll
      for (int e = 0; e < NEXP; ++e) {
        if (e == e0) continue;
        if (e1 < 0 || lg[e] > lg[e1]) e1 = e;
      }
      float tv = expf(lg[e1] - lg[e0]);
      float w0 = 1.0f / (1.0f + tv);
      float w1 = tv * w0;
      epacked[tok] = e0 | (e1 << 8);
      wpair[tok] = make_float2(w0, w1);
      atomicAdd(&lhist[e0], 1);
      atomicAdd(&lhist[8 + e1], 1);
    }
  }
  __syncthreads();
  if (tid < 16) hist[b * 16 + tid] = lhist[tid];
}

// scatter: per-block exclusive prefix over histograms -> routed lists.
__global__ __launch_bounds__(256) void scatter_kernel(
    const int* __restrict__ hist, const int* __restrict__ epacked,
    const float2* __restrict__ wpair, int* __restrict__ counts,
    int* __restrict__ lists, float* __restrict__ wlists) {
  __shared__ int partial[16][17];
  __shared__ int base[16];
  __shared__ int cnt2[16];
  int tid = threadIdx.x;
  int b = blockIdx.x;
  int bin = tid & 15, grp = tid >> 4;
  int s = 0;
  for (int i = 0; i < 16; ++i) {
    int bb = grp * 16 + i;
    if (bb < b) s += hist[bb * 16 + bin];
  }
  partial[grp][bin] = s;
  if (tid < 16) cnt2[tid] = 0;
  __syncthreads();
  if (tid < 16) {
    int s2 = 0;
#pragma unroll
    for (int g = 0; g < 16; ++g) s2 += partial[g][tid];
    base[tid] = s2;
  }
  __syncthreads();
  if (tid < 64) {
    int tok = b * 32 + (tid >> 1);
    int slot = tid & 1;
    int ep = epacked[tok];
    int e = slot ? ((ep >> 8) & 255) : (ep & 255);
    float2 wp = wpair[tok];
    float wv = slot ? wp.y : wp.x;
    int bn = slot * 8 + e;
    int pos = base[bn] + atomicAdd(&cnt2[bn], 1);
    lists[bn * TOKENS + pos] = tok;
    wlists[bn * TOKENS + pos] = wv;
  }
  if (b == 255) {
    __syncthreads();
    if (tid < 16) counts[tid] = base[tid] + cnt2[tid];
  }
}

// 128M x 256N x BK64 grouped GEMM, 512 threads / 8 waves (2M x 4N).
// Per-wave shape IDENTICAL to r7's proven kernel: 64x64 out, acc[4][4]
// (VGPR 104 — under the toolchain's hard 128-VGPR cap for 512-thr blocks,
// so NO spill, unlike every acc[8][*] attempt r5/r8/r9/r10).
// Why 256-wide N: halves A re-reads -> staged traffic 530->384 MB, which
// r7's counters showed is the binding constraint (~4.9 TB/s effective).
// Single-buffer 48KB LDS -> 2 blocks/CU (VGPR-capped); 512 active blocks
// = exact fill. Serial 2-barrier loop (r4-proven at this occupancy).
// Atomic epilogue onto pre-zeroed out (r4-proven, ~65MB writes).
__global__ __launch_bounds__(512) void moe_gemm_wide(
    const unsigned short* __restrict__ xb, const unsigned short* __restrict__ Web,
    const float* __restrict__ be, const int* __restrict__ counts,
    const int* __restrict__ lists, const float* __restrict__ wlists,
    float* __restrict__ out) {
  int bz = blockIdx.z;           // slot*8 + expert
  int e = bz & 7;
  int cnt = counts[bz];
  int mbase = blockIdx.y * 128;  // 16 M-tiles -> 2048-token capacity
  if (mbase >= cnt) return;
  int nbase = blockIdx.x * 256;  // 4 N-tiles
  const int* lst = lists + bz * TOKENS;
  const float* wl = wlists + bz * TOKENS;

  // single buffer; stored 16B-chunk cs at row r holds logical chunk cs^(r&7)
  __shared__ alignas(128) unsigned short lA[128 * 64];  // 16 KiB
  __shared__ alignas(128) unsigned short lB[256 * 64];  // 32 KiB

  int tid = threadIdx.x;         // 0..511
  int lane = tid & 63;
  int w = tid >> 6;              // wave 0..7
  int wm = w >> 2, wn = w & 3;   // 2M x 4N; wave output 64x64
  int lm = lane & 15, lk = lane >> 4;

  // A: 1024 chunks (128 rows x 8); thread covers L = j*512 + tid, j=0..1
  // B: 2048 chunks (256 rows x 8); j=0..3
  // chunk L: row r=L>>3, stored cs=L&7, source logical c = cs^(r&7) (rule 21)
  const unsigned short* aga[2];
#pragma unroll
  for (int j = 0; j < 2; ++j) {
    int L = j * 512 + tid;
    int r = L >> 3, cs = L & 7;
    int c = cs ^ (r & 7);
    int gr = mbase + r; if (gr >= cnt) gr = cnt - 1;
    aga[j] = xb + (size_t)lst[gr] * KDIM + c * 8;
  }
  const unsigned short* bga[4];
#pragma unroll
  for (int j = 0; j < 4; ++j) {
    int L = j * 512 + tid;
    int r = L >> 3, cs = L & 7;
    int c = cs ^ (r & 7);
    bga[j] = Web + (size_t)e * (NDIM * KDIM) + (size_t)(nbase + r) * KDIM + c * 8;
  }

#define STAGE(kt)                                                             \
  {                                                                           \
    _Pragma("unroll") for (int j = 0; j < 2; ++j)                             \
      gload_lds16(aga[j] + (kt) * 64, (char*)lA + j * 8192 + w * 1024);       \
    _Pragma("unroll") for (int j = 0; j < 4; ++j)                             \
      gload_lds16(bga[j] + (kt) * 64, (char*)lB + j * 8192 + w * 1024);       \
  }

  f32x4 acc[4][4] = {};

#define COMPUTE                                                               \
  {                                                                           \
    _Pragma("unroll") for (int ks = 0; ks < 2; ++ks) {                        \
      short8v af[4], bfv[4];                                                  \
      _Pragma("unroll") for (int mi = 0; mi < 4; ++mi) {                      \
        int row = wm * 64 + mi * 16 + lm;                                     \
        int cs = (ks * 4 + lk) ^ (row & 7);                                   \
        af[mi] = *reinterpret_cast<const short8v*>(&lA[row * 64 + cs * 8]);   \
      }                                                                       \
      _Pragma("unroll") for (int nj = 0; nj < 4; ++nj) {                      \
        int row = wn * 64 + nj * 16 + lm;                                     \
        int cs = (ks * 4 + lk) ^ (row & 7);                                   \
        bfv[nj] = *reinterpret_cast<const short8v*>(&lB[row * 64 + cs * 8]);  \
      }                                                                       \
      _Pragma("unroll") for (int mi = 0; mi < 4; ++mi)                        \
        _Pragma("unroll") for (int nj = 0; nj < 4; ++nj)                      \
          acc[mi][nj] = __builtin_amdgcn_mfma_f32_16x16x32_bf16(              \
              af[mi], bfv[nj], acc[mi][nj], 0, 0, 0);                         \
    }                                                                         \
  }

  for (int kt = 0; kt < 16; ++kt) {
    __syncthreads();   // previous COMPUTE's ds_reads done before overwrite
    STAGE(kt);
    __syncthreads();   // drains vmcnt(0) before s_barrier -> tile ready
    COMPUTE;
  }
#undef STAGE
#undef COMPUTE

  // epilogue: C/D mapping col=lane&15, row=(lane>>4)*4+reg  [m89/m91]
  float bev[4];
#pragma unroll
  for (int nj = 0; nj < 4; ++nj)
    bev[nj] = be[e * NDIM + nbase + wn * 64 + nj * 16 + lm];
#pragma unroll
  for (int mi = 0; mi < 4; ++mi) {
#pragma unroll
    for (int r = 0; r < 4; ++r) {
      int grow = mbase + wm * 64 + mi * 16 + lk * 4 + r;
      if (grow >= cnt) continue;
      int tokn = lst[grow];
      float wgt = wl[grow];
      float* orow = out + (size_t)tokn * NDIM + nbase + wn * 64 + lm;
#pragma unroll
      for (int nj = 0; nj < 4; ++nj)
        unsafeAtomicAdd(&orow[nj * 16], wgt * (acc[mi][nj][r] + bev[nj]));
    }
  }
}

// ============================ DEEP FALLBACK (round-1) ============================

__global__ __launch_bounds__(256) void gate_kernel(
    const float* __restrict__ x, const float* __restrict__ Wg,
    const float* __restrict__ bg, int* __restrict__ counts,
    int* __restrict__ lists, float* __restrict__ wlists) {
  int gtid = blockIdx.x * blockDim.x + threadIdx.x;
  int tok = gtid >> 6;
  int lane = threadIdx.x & 63;
  if (tok >= TOKENS) return;
  const float* xr = x + (size_t)tok * KDIM + lane * 16;
  float acc[NEXP] = {};
#pragma unroll
  for (int j4 = 0; j4 < 4; ++j4) {
    float4 xv = *reinterpret_cast<const float4*>(xr + j4 * 4);
    float xs[4] = {xv.x, xv.y, xv.z, xv.w};
#pragma unroll
    for (int jj = 0; jj < 4; ++jj) {
      int k = lane * 16 + j4 * 4 + jj;
      const float4* wr = reinterpret_cast<const float4*>(Wg + k * NEXP);
      float4 w0 = wr[0], w1 = wr[1];
      float xv1 = xs[jj];
      acc[0] += xv1 * w0.x; acc[1] += xv1 * w0.y;
      acc[2] += xv1 * w0.z; acc[3] += xv1 * w0.w;
      acc[4] += xv1 * w1.x; acc[5] += xv1 * w1.y;
      acc[6] += xv1 * w1.z; acc[7] += xv1 * w1.w;
    }
  }
#pragma unroll
  for (int e = 0; e < NEXP; ++e) {
    acc[e] += __shfl_xor(acc[e], 1, 64);
    acc[e] += __shfl_xor(acc[e], 2, 64);
    acc[e] += __shfl_xor(acc[e], 4, 64);
    acc[e] += __shfl_xor(acc[e], 8, 64);
    acc[e] += __shfl_xor(acc[e], 16, 64);
    acc[e] += __shfl_xor(acc[e], 32, 64);
  }
  if (lane == 0) {
    float lg[NEXP];
#pragma unroll
    for (int e = 0; e < NEXP; ++e) lg[e] = acc[e] + bg[e];
    int e0 = 0;
#pragma unroll
    for (int e = 1; e < NEXP; ++e) if (lg[e] > lg[e0]) e0 = e;
    int e1 = -1;
#pragma unroll
    for (int e = 0; e < NEXP; ++e) {
      if (e == e0) continue;
      if (e1 < 0 || lg[e] > lg[e1]) e1 = e;
    }
    float t = expf(lg[e1] - lg[e0]);
    float w0 = 1.0f / (1.0f + t);
    float w1 = t * w0;
    int p0 = atomicAdd(&counts[e0], 1);
    lists[e0 * TOKENS + p0] = tok;
    wlists[e0 * TOKENS + p0] = w0;
    int p1 = atomicAdd(&counts[NEXP + e1], 1);
    lists[(NEXP + e1) * TOKENS + p1] = tok;
    wlists[(NEXP + e1) * TOKENS + p1] = w1;
  }
}

template <int ACCUM>
__global__ __launch_bounds__(256) void moe_gemm(
    const float* __restrict__ x, const float* __restrict__ We,
    const float* __restrict__ be, const int* __restrict__ counts,
    const int* __restrict__ lists, const float* __restrict__ wlists,
    float* __restrict__ out, int slot) {
  int e = blockIdx.z;
  int cnt = counts[slot * NEXP + e];
  int mbase = blockIdx.y * 128;
  if (mbase >= cnt) return;
  int nbase = blockIdx.x * 128;
  const int* lst = lists + (slot * NEXP + e) * TOKENS;
  const float* wl = wlists + (slot * NEXP + e) * TOKENS;
  __shared__ ushort8v lA[1024];
  __shared__ ushort8v lB[1024];
  int tid = threadIdx.x;
  int lane = tid & 63;
  int w = tid >> 6;
  int wm = w >> 1, wn = w & 1;
  const float* aptr[4];
  const float* bptr[4];
  int sw[4];
#pragma unroll
  for (int i = 0; i < 4; ++i) {
    int c = i * 256 + tid;
    int r = c >> 3, cc = c & 7;
    int gr = mbase + r;
    if (gr >= cnt) gr = cnt - 1;
    int tokn = lst[gr];
    aptr[i] = x + (size_t)tokn * KDIM + cc * 8;
    bptr[i] = We + (size_t)e * (NDIM * KDIM) + (size_t)(nbase + r) * KDIM + cc * 8;
    sw[i] = r * 8 + (cc ^ (r & 7));
  }
  f32x4 acc[4][4] = {};
  int lm = lane & 15, lk = lane >> 4;
  for (int kt = 0; kt < KDIM / 64; ++kt) {
    __syncthreads();
#pragma unroll
    for (int i = 0; i < 4; ++i) {
      float4 f0 = *reinterpret_cast<const float4*>(aptr[i] + kt * 64);
      float4 f1 = *reinterpret_cast<const float4*>(aptr[i] + kt * 64 + 4);
      ushort8v v;
      v[0] = f2bf(f0.x); v[1] = f2bf(f0.y); v[2] = f2bf(f0.z); v[3] = f2bf(f0.w);
      v[4] = f2bf(f1.x); v[5] = f2bf(f1.y); v[6] = f2bf(f1.z); v[7] = f2bf(f1.w);
      lA[sw[i]] = v;
      float4 g0 = *reinterpret_cast<const float4*>(bptr[i] + kt * 64);
      float4 g1 = *reinterpret_cast<const float4*>(bptr[i] + kt * 64 + 4);
      ushort8v u;
      u[0] = f2bf(g0.x); u[1] = f2bf(g0.y); u[2] = f2bf(g0.z); u[3] = f2bf(g0.w);
      u[4] = f2bf(g1.x); u[5] = f2bf(g1.y); u[6] = f2bf(g1.z); u[7] = f2bf(g1.w);
      lB[sw[i]] = u;
    }
    __syncthreads();
#pragma unroll
    for (int ks = 0; ks < 2; ++ks) {
      short8v af[4], bfv[4];
#pragma unroll
      for (int mi = 0; mi < 4; ++mi) {
        int row = wm * 64 + mi * 16 + lm;
        int cidx = (ks * 4 + lk) ^ (row & 7);
        af[mi] = *reinterpret_cast<const short8v*>(&lA[row * 8 + cidx]);
      }
#pragma unroll
      for (int nj = 0; nj < 4; ++nj) {
        int row = wn * 64 + nj * 16 + lm;
        int cidx = (ks * 4 + lk) ^ (row & 7);
        bfv[nj] = *reinterpret_cast<const short8v*>(&lB[row * 8 + cidx]);
      }
#pragma unroll
      for (int mi = 0; mi < 4; ++mi)
#pragma unroll
        for (int nj = 0; nj < 4; ++nj)
          acc[mi][nj] = __builtin_amdgcn_mfma_f32_16x16x32_bf16(
              af[mi], bfv[nj], acc[mi][nj], 0, 0, 0);
    }
  }
  float bev[4];
#pragma unroll
  for (int nj = 0; nj < 4; ++nj)
    bev[nj] = be[e * NDIM + nbase + wn * 64 + nj * 16 + lm];
#pragma unroll
  for (int mi = 0; mi < 4; ++mi) {
#pragma unroll
    for (int r = 0; r < 4; ++r) {
      int grow = mbase + wm * 64 + mi * 16 + lk * 4 + r;
      if (grow >= cnt) continue;
      int tokn = lst[grow];
      float wgt = wl[grow];
      float* orow = out + (size_t)tokn * NDIM + nbase + wn * 64 + lm;
#pragma unroll
      for (int nj = 0; nj < 4; ++nj) {
        float val = wgt * (acc[mi][nj][r] + bev[nj]);
        if (ACCUM) orow[nj * 16] += val;
        else       orow[nj * 16] = val;
      }
    }
  }
}

// ============================ HOST ============================

extern "C" void kernel_launch(void* const* d_in, const int* in_sizes, int n_in,
                              void* d_out, int out_size, void* d_ws, size_t ws_size,
                              hipStream_t stream) {
  const float* x  = (const float*)d_in[0];
  const float* Wg = (const float*)d_in[1];
  const float* bg = (const float*)d_in[2];
  const float* We = (const float*)d_in[3];
  const float* be = (const float*)d_in[4];
  float* out = (float*)d_out;

  char* p = (char*)d_ws;
  int*   counts = (int*)p;                 p += 256;
  int*   lists  = (int*)p;                 p += (size_t)16 * TOKENS * 4;  // 512 KB
  float* wlists = (float*)p;               p += (size_t)16 * TOKENS * 4;  // 512 KB
  int*   epacked = (int*)p;                p += (size_t)TOKENS * 4;       // 32 KB
  float2* wpair  = (float2*)p;             p += (size_t)TOKENS * 8;       // 64 KB
  int*   hist    = (int*)p;                p += 256 * 16 * 4;             // 16 KB
  unsigned short* xbuf = (unsigned short*)p; p += (size_t)TOKENS * KDIM * 2;       // 16 MB
  unsigned short* Webf = (unsigned short*)p; p += (size_t)NEXP * NDIM * KDIM * 2;  // 16 MB
  size_t need = (size_t)(p - (char*)d_ws);

  if (ws_size >= need) {
    gate_conv_kernel<<<5376, 256, 0, stream>>>(
        x, Wg, bg, We, xbuf, Webf, epacked, wpair, hist, out);
    scatter_kernel<<<256, 256, 0, stream>>>(hist, epacked, wpair, counts, lists, wlists);
    dim3 grid(NDIM / 256, 16, 16);  // 4 N x 16 M (2048 cap) x 16 groups
    moe_gemm_wide<<<grid, 512, 0, stream>>>(xbuf, Webf, be, counts, lists, wlists, out);
  } else {
    dim3 grid(NDIM / 128, TOKENS / 128, NEXP);
    hipMemsetAsync(d_ws, 0, 64, stream);
    gate_kernel<<<TOKENS / 4, 256, 0, stream>>>(x, Wg, bg, counts, lists, wlists);
    moe_gemm<0><<<grid, 256, 0, stream>>>(x, We, be, counts, lists, wlists, out, 0);
    moe_gemm<1><<<grid, 256, 0, stream>>>(x, We, be, counts, lists, wlists, out, 1);
  }
}

// Round 14
// 118.058 us; speedup vs baseline: 3.9627x; 1.1759x over previous
//
#include <hip/hip_runtime.h>
#include <hip/hip_bf16.h>

#define TOKENS 8192
#define KDIM 1024
#define NDIM 1024
#define NEXP 8

typedef __attribute__((ext_vector_type(8))) short short8v;
typedef __attribute__((ext_vector_type(8))) unsigned short ushort8v;
typedef __attribute__((ext_vector_type(4))) float f32x4;

__device__ inline unsigned short f2bf(float f) {
  unsigned int u = __float_as_uint(f);
  u += 0x7fffu + ((u >> 16) & 1u);
  return (unsigned short)(u >> 16);
}

__device__ inline void gload_lds16(const void* g, void* l) {
  __builtin_amdgcn_global_load_lds(
      (const __attribute__((address_space(1))) unsigned int*)g,
      (__attribute__((address_space(3))) unsigned int*)l, 16, 0, 0);
}

// ============================ FAST PATH ============================

// Fused: [0,256) gating + x->bf16; [256,4352) We->bf16; [4352,5376) zero out
// (zero blocks only launched on the mid/atomic path).
__global__ __launch_bounds__(256) void gate_conv_kernel(
    const float* __restrict__ x, const float* __restrict__ Wg,
    const float* __restrict__ bg, const float* __restrict__ We,
    unsigned short* __restrict__ xb, unsigned short* __restrict__ Web,
    int* __restrict__ epacked, float2* __restrict__ wpair,
    int* __restrict__ hist, float* __restrict__ out) {
  int b = blockIdx.x;
  int tid = threadIdx.x;
  if (b >= 4352) {
    float4* o = reinterpret_cast<float4*>(out) + (size_t)(b - 4352) * 2048 + tid;
    float4 z = make_float4(0.f, 0.f, 0.f, 0.f);
#pragma unroll
    for (int i = 0; i < 8; ++i) o[i * 256] = z;
    return;
  }
  if (b >= 256) {
    size_t i = (size_t)(b - 256) * 256 + tid;
    const float4* s = reinterpret_cast<const float4*>(We + i * 8);
    float4 a = s[0], c = s[1];
    ushort8v v;
    v[0] = f2bf(a.x); v[1] = f2bf(a.y); v[2] = f2bf(a.z); v[3] = f2bf(a.w);
    v[4] = f2bf(c.x); v[5] = f2bf(c.y); v[6] = f2bf(c.z); v[7] = f2bf(c.w);
    *reinterpret_cast<ushort8v*>(Web + i * 8) = v;
    return;
  }
  __shared__ int lhist[16];
  if (tid < 16) lhist[tid] = 0;
  __syncthreads();
  int w = tid >> 6, lane = tid & 63;
  int tok0 = b * 32 + w * 8;

  for (int t = 0; t < 8; ++t) {
    int tok = tok0 + t;
    const float* xr = x + (size_t)tok * KDIM + lane * 16;
    float acc[NEXP] = {};
    ushort8v xv0, xv1;
#pragma unroll
    for (int j4 = 0; j4 < 4; ++j4) {
      float4 xv = *reinterpret_cast<const float4*>(xr + j4 * 4);
      float xs[4] = {xv.x, xv.y, xv.z, xv.w};
#pragma unroll
      for (int jj = 0; jj < 4; ++jj) {
        int k = lane * 16 + j4 * 4 + jj;
        const float4* wr = reinterpret_cast<const float4*>(Wg + k * NEXP);
        float4 w0 = wr[0], w1 = wr[1];
        float xf = xs[jj];
        acc[0] += xf * w0.x; acc[1] += xf * w0.y;
        acc[2] += xf * w0.z; acc[3] += xf * w0.w;
        acc[4] += xf * w1.x; acc[5] += xf * w1.y;
        acc[6] += xf * w1.z; acc[7] += xf * w1.w;
        int li = j4 * 4 + jj;
        unsigned short bv = f2bf(xf);
        if (li < 8) xv0[li] = bv; else xv1[li - 8] = bv;
      }
    }
    unsigned short* xrow = xb + (size_t)tok * KDIM + lane * 16;
    *reinterpret_cast<ushort8v*>(xrow) = xv0;
    *reinterpret_cast<ushort8v*>(xrow + 8) = xv1;
#pragma unroll
    for (int e = 0; e < NEXP; ++e) {
      acc[e] += __shfl_xor(acc[e], 1, 64);
      acc[e] += __shfl_xor(acc[e], 2, 64);
      acc[e] += __shfl_xor(acc[e], 4, 64);
      acc[e] += __shfl_xor(acc[e], 8, 64);
      acc[e] += __shfl_xor(acc[e], 16, 64);
      acc[e] += __shfl_xor(acc[e], 32, 64);
    }
    if (lane == 0) {
      float lg[NEXP];
#pragma unroll
      for (int e = 0; e < NEXP; ++e) lg[e] = acc[e] + bg[e];
      int e0 = 0;
#pragma unroll
      for (int e = 1; e < NEXP; ++e) if (lg[e] > lg[e0]) e0 = e;
      int e1 = -1;
#pragma unroll
      for (int e = 0; e < NEXP; ++e) {
        if (e == e0) continue;
        if (e1 < 0 || lg[e] > lg[e1]) e1 = e;
      }
      float tv = expf(lg[e1] - lg[e0]);
      float w0 = 1.0f / (1.0f + tv);
      float w1 = tv * w0;
      epacked[tok] = e0 | (e1 << 8);
      wpair[tok] = make_float2(w0, w1);
      atomicAdd(&lhist[e0], 1);
      atomicAdd(&lhist[8 + e1], 1);
    }
  }
  __syncthreads();
  if (tid < 16) hist[b * 16 + tid] = lhist[tid];
}

// scatter: per-block exclusive prefix over histograms -> routed lists.
__global__ __launch_bounds__(256) void scatter_kernel(
    const int* __restrict__ hist, const int* __restrict__ epacked,
    const float2* __restrict__ wpair, int* __restrict__ counts,
    int* __restrict__ lists, float* __restrict__ wlists) {
  __shared__ int partial[16][17];
  __shared__ int base[16];
  __shared__ int cnt2[16];
  int tid = threadIdx.x;
  int b = blockIdx.x;
  int bin = tid & 15, grp = tid >> 4;
  int s = 0;
  for (int i = 0; i < 16; ++i) {
    int bb = grp * 16 + i;
    if (bb < b) s += hist[bb * 16 + bin];
  }
  partial[grp][bin] = s;
  if (tid < 16) cnt2[tid] = 0;
  __syncthreads();
  if (tid < 16) {
    int s2 = 0;
#pragma unroll
    for (int g = 0; g < 16; ++g) s2 += partial[g][tid];
    base[tid] = s2;
  }
  __syncthreads();
  if (tid < 64) {
    int tok = b * 32 + (tid >> 1);
    int slot = tid & 1;
    int ep = epacked[tok];
    int e = slot ? ((ep >> 8) & 255) : (ep & 255);
    float2 wp = wpair[tok];
    float wv = slot ? wp.y : wp.x;
    int bn = slot * 8 + e;
    int pos = base[bn] + atomicAdd(&cnt2[bn], 1);
    lists[bn * TOKENS + pos] = tok;
    wlists[bn * TOKENS + pos] = wv;
  }
  if (b == 255) {
    __syncthreads();
    if (tid < 16) counts[tid] = base[tid] + cnt2[tid];
  }
}

// 128M x 256N x BK64 grouped GEMM (r13-proven shape: 512 thr / 8 waves 2Mx4N,
// per-wave 64x64 acc[4][4], VGPR 64, no spill, GEMM loop = clean counters).
// PLAIN=1: slot-split plain stores (slot0->out, slot1->p1; each slot's lists
//   cover every token exactly once -> disjoint full covers, no atomics).
//   A/B vs r13's atomic epilogue to isolate the 16.7M device-scope atomicAdds
//   (suspected ~55us coherence-point serialization).
// PLAIN=0: r13 atomic epilogue (requires pre-zeroed out).
template <int PLAIN>
__global__ __launch_bounds__(512) void moe_gemm_wide(
    const unsigned short* __restrict__ xb, const unsigned short* __restrict__ Web,
    const float* __restrict__ be, const int* __restrict__ counts,
    const int* __restrict__ lists, const float* __restrict__ wlists,
    float* __restrict__ out, float* __restrict__ p1) {
  int bz = blockIdx.z;           // slot*8 + expert
  int e = bz & 7;
  int slot = bz >> 3;
  int cnt = counts[bz];
  int mbase = blockIdx.y * 128;  // 16 M-tiles -> 2048-token capacity
  if (mbase >= cnt) return;
  int nbase = blockIdx.x * 256;  // 4 N-tiles
  const int* lst = lists + bz * TOKENS;
  const float* wl = wlists + bz * TOKENS;

  __shared__ alignas(128) unsigned short lA[128 * 64];  // 16 KiB
  __shared__ alignas(128) unsigned short lB[256 * 64];  // 32 KiB

  int tid = threadIdx.x;
  int lane = tid & 63;
  int w = tid >> 6;
  int wm = w >> 2, wn = w & 3;   // 2M x 4N; wave output 64x64
  int lm = lane & 15, lk = lane >> 4;

  const unsigned short* aga[2];
#pragma unroll
  for (int j = 0; j < 2; ++j) {
    int L = j * 512 + tid;
    int r = L >> 3, cs = L & 7;
    int c = cs ^ (r & 7);        // pre-swizzled source (rule 21)
    int gr = mbase + r; if (gr >= cnt) gr = cnt - 1;
    aga[j] = xb + (size_t)lst[gr] * KDIM + c * 8;
  }
  const unsigned short* bga[4];
#pragma unroll
  for (int j = 0; j < 4; ++j) {
    int L = j * 512 + tid;
    int r = L >> 3, cs = L & 7;
    int c = cs ^ (r & 7);
    bga[j] = Web + (size_t)e * (NDIM * KDIM) + (size_t)(nbase + r) * KDIM + c * 8;
  }

#define STAGE(kt)                                                             \
  {                                                                           \
    _Pragma("unroll") for (int j = 0; j < 2; ++j)                             \
      gload_lds16(aga[j] + (kt) * 64, (char*)lA + j * 8192 + w * 1024);       \
    _Pragma("unroll") for (int j = 0; j < 4; ++j)                             \
      gload_lds16(bga[j] + (kt) * 64, (char*)lB + j * 8192 + w * 1024);       \
  }

  f32x4 acc[4][4] = {};

#define COMPUTE                                                               \
  {                                                                           \
    _Pragma("unroll") for (int ks = 0; ks < 2; ++ks) {                        \
      short8v af[4], bfv[4];                                                  \
      _Pragma("unroll") for (int mi = 0; mi < 4; ++mi) {                      \
        int row = wm * 64 + mi * 16 + lm;                                     \
        int cs = (ks * 4 + lk) ^ (row & 7);                                   \
        af[mi] = *reinterpret_cast<const short8v*>(&lA[row * 64 + cs * 8]);   \
      }                                                                       \
      _Pragma("unroll") for (int nj = 0; nj < 4; ++nj) {                      \
        int row = wn * 64 + nj * 16 + lm;                                     \
        int cs = (ks * 4 + lk) ^ (row & 7);                                   \
        bfv[nj] = *reinterpret_cast<const short8v*>(&lB[row * 64 + cs * 8]);  \
      }                                                                       \
      _Pragma("unroll") for (int mi = 0; mi < 4; ++mi)                        \
        _Pragma("unroll") for (int nj = 0; nj < 4; ++nj)                      \
          acc[mi][nj] = __builtin_amdgcn_mfma_f32_16x16x32_bf16(              \
              af[mi], bfv[nj], acc[mi][nj], 0, 0, 0);                         \
    }                                                                         \
  }

  for (int kt = 0; kt < 16; ++kt) {
    __syncthreads();
    STAGE(kt);
    __syncthreads();
    COMPUTE;
  }
#undef STAGE
#undef COMPUTE

  // epilogue: C/D mapping col=lane&15, row=(lane>>4)*4+reg  [m89/m91]
  float* dst = (PLAIN && slot) ? p1 : out;
  float bev[4];
#pragma unroll
  for (int nj = 0; nj < 4; ++nj)
    bev[nj] = be[e * NDIM + nbase + wn * 64 + nj * 16 + lm];
#pragma unroll
  for (int mi = 0; mi < 4; ++mi) {
#pragma unroll
    for (int r = 0; r < 4; ++r) {
      int grow = mbase + wm * 64 + mi * 16 + lk * 4 + r;
      if (grow >= cnt) continue;
      int tokn = lst[grow];
      float wgt = wl[grow];
      float* orow = dst + (size_t)tokn * NDIM + nbase + wn * 64 + lm;
#pragma unroll
      for (int nj = 0; nj < 4; ++nj) {
        float val = wgt * (acc[mi][nj][r] + bev[nj]);
        if (PLAIN) orow[nj * 16] = val;
        else       unsafeAtomicAdd(&orow[nj * 16], val);
      }
    }
  }
}

// out += p1 (both full disjoint single-writer covers)
__global__ __launch_bounds__(256) void combine_kernel(
    float* __restrict__ out, const float* __restrict__ p1) {
  size_t i = (size_t)blockIdx.x * 256 + threadIdx.x;
  float4 a = reinterpret_cast<const float4*>(p1)[i];
  float4 b = reinterpret_cast<float4*>(out)[i];
  b.x += a.x; b.y += a.y; b.z += a.z; b.w += a.w;
  reinterpret_cast<float4*>(out)[i] = b;
}

// ============================ DEEP FALLBACK (round-1) ============================

__global__ __launch_bounds__(256) void gate_kernel(
    const float* __restrict__ x, const float* __restrict__ Wg,
    const float* __restrict__ bg, int* __restrict__ counts,
    int* __restrict__ lists, float* __restrict__ wlists) {
  int gtid = blockIdx.x * blockDim.x + threadIdx.x;
  int tok = gtid >> 6;
  int lane = threadIdx.x & 63;
  if (tok >= TOKENS) return;
  const float* xr = x + (size_t)tok * KDIM + lane * 16;
  float acc[NEXP] = {};
#pragma unroll
  for (int j4 = 0; j4 < 4; ++j4) {
    float4 xv = *reinterpret_cast<const float4*>(xr + j4 * 4);
    float xs[4] = {xv.x, xv.y, xv.z, xv.w};
#pragma unroll
    for (int jj = 0; jj < 4; ++jj) {
      int k = lane * 16 + j4 * 4 + jj;
      const float4* wr = reinterpret_cast<const float4*>(Wg + k * NEXP);
      float4 w0 = wr[0], w1 = wr[1];
      float xv1 = xs[jj];
      acc[0] += xv1 * w0.x; acc[1] += xv1 * w0.y;
      acc[2] += xv1 * w0.z; acc[3] += xv1 * w0.w;
      acc[4] += xv1 * w1.x; acc[5] += xv1 * w1.y;
      acc[6] += xv1 * w1.z; acc[7] += xv1 * w1.w;
    }
  }
#pragma unroll
  for (int e = 0; e < NEXP; ++e) {
    acc[e] += __shfl_xor(acc[e], 1, 64);
    acc[e] += __shfl_xor(acc[e], 2, 64);
    acc[e] += __shfl_xor(acc[e], 4, 64);
    acc[e] += __shfl_xor(acc[e], 8, 64);
    acc[e] += __shfl_xor(acc[e], 16, 64);
    acc[e] += __shfl_xor(acc[e], 32, 64);
  }
  if (lane == 0) {
    float lg[NEXP];
#pragma unroll
    for (int e = 0; e < NEXP; ++e) lg[e] = acc[e] + bg[e];
    int e0 = 0;
#pragma unroll
    for (int e = 1; e < NEXP; ++e) if (lg[e] > lg[e0]) e0 = e;
    int e1 = -1;
#pragma unroll
    for (int e = 0; e < NEXP; ++e) {
      if (e == e0) continue;
      if (e1 < 0 || lg[e] > lg[e1]) e1 = e;
    }
    float t = expf(lg[e1] - lg[e0]);
    float w0 = 1.0f / (1.0f + t);
    float w1 = t * w0;
    int p0 = atomicAdd(&counts[e0], 1);
    lists[e0 * TOKENS + p0] = tok;
    wlists[e0 * TOKENS + p0] = w0;
    int p1 = atomicAdd(&counts[NEXP + e1], 1);
    lists[(NEXP + e1) * TOKENS + p1] = tok;
    wlists[(NEXP + e1) * TOKENS + p1] = w1;
  }
}

template <int ACCUM>
__global__ __launch_bounds__(256) void moe_gemm(
    const float* __restrict__ x, const float* __restrict__ We,
    const float* __restrict__ be, const int* __restrict__ counts,
    const int* __restrict__ lists, const float* __restrict__ wlists,
    float* __restrict__ out, int slot) {
  int e = blockIdx.z;
  int cnt = counts[slot * NEXP + e];
  int mbase = blockIdx.y * 128;
  if (mbase >= cnt) return;
  int nbase = blockIdx.x * 128;
  const int* lst = lists + (slot * NEXP + e) * TOKENS;
  const float* wl = wlists + (slot * NEXP + e) * TOKENS;
  __shared__ ushort8v lA[1024];
  __shared__ ushort8v lB[1024];
  int tid = threadIdx.x;
  int lane = tid & 63;
  int w = tid >> 6;
  int wm = w >> 1, wn = w & 1;
  const float* aptr[4];
  const float* bptr[4];
  int sw[4];
#pragma unroll
  for (int i = 0; i < 4; ++i) {
    int c = i * 256 + tid;
    int r = c >> 3, cc = c & 7;
    int gr = mbase + r;
    if (gr >= cnt) gr = cnt - 1;
    int tokn = lst[gr];
    aptr[i] = x + (size_t)tokn * KDIM + cc * 8;
    bptr[i] = We + (size_t)e * (NDIM * KDIM) + (size_t)(nbase + r) * KDIM + cc * 8;
    sw[i] = r * 8 + (cc ^ (r & 7));
  }
  f32x4 acc[4][4] = {};
  int lm = lane & 15, lk = lane >> 4;
  for (int kt = 0; kt < KDIM / 64; ++kt) {
    __syncthreads();
#pragma unroll
    for (int i = 0; i < 4; ++i) {
      float4 f0 = *reinterpret_cast<const float4*>(aptr[i] + kt * 64);
      float4 f1 = *reinterpret_cast<const float4*>(aptr[i] + kt * 64 + 4);
      ushort8v v;
      v[0] = f2bf(f0.x); v[1] = f2bf(f0.y); v[2] = f2bf(f0.z); v[3] = f2bf(f0.w);
      v[4] = f2bf(f1.x); v[5] = f2bf(f1.y); v[6] = f2bf(f1.z); v[7] = f2bf(f1.w);
      lA[sw[i]] = v;
      float4 g0 = *reinterpret_cast<const float4*>(bptr[i] + kt * 64);
      float4 g1 = *reinterpret_cast<const float4*>(bptr[i] + kt * 64 + 4);
      ushort8v u;
      u[0] = f2bf(g0.x); u[1] = f2bf(g0.y); u[2] = f2bf(g0.z); u[3] = f2bf(g0.w);
      u[4] = f2bf(g1.x); u[5] = f2bf(g1.y); u[6] = f2bf(g1.z); u[7] = f2bf(g1.w);
      lB[sw[i]] = u;
    }
    __syncthreads();
#pragma unroll
    for (int ks = 0; ks < 2; ++ks) {
      short8v af[4], bfv[4];
#pragma unroll
      for (int mi = 0; mi < 4; ++mi) {
        int row = wm * 64 + mi * 16 + lm;
        int cidx = (ks * 4 + lk) ^ (row & 7);
        af[mi] = *reinterpret_cast<const short8v*>(&lA[row * 8 + cidx]);
      }
#pragma unroll
      for (int nj = 0; nj < 4; ++nj) {
        int row = wn * 64 + nj * 16 + lm;
        int cidx = (ks * 4 + lk) ^ (row & 7);
        bfv[nj] = *reinterpret_cast<const short8v*>(&lB[row * 8 + cidx]);
      }
#pragma unroll
      for (int mi = 0; mi < 4; ++mi)
#pragma unroll
        for (int nj = 0; nj < 4; ++nj)
          acc[mi][nj] = __builtin_amdgcn_mfma_f32_16x16x32_bf16(
              af[mi], bfv[nj], acc[mi][nj], 0, 0, 0);
    }
  }
  float bev[4];
#pragma unroll
  for (int nj = 0; nj < 4; ++nj)
    bev[nj] = be[e * NDIM + nbase + wn * 64 + nj * 16 + lm];
#pragma unroll
  for (int mi = 0; mi < 4; ++mi) {
#pragma unroll
    for (int r = 0; r < 4; ++r) {
      int grow = mbase + wm * 64 + mi * 16 + lk * 4 + r;
      if (grow >= cnt) continue;
      int tokn = lst[grow];
      float wgt = wl[grow];
      float* orow = out + (size_t)tokn * NDIM + nbase + wn * 64 + lm;
#pragma unroll
      for (int nj = 0; nj < 4; ++nj) {
        float val = wgt * (acc[mi][nj][r] + bev[nj]);
        if (ACCUM) orow[nj * 16] += val;
        else       orow[nj * 16] = val;
      }
    }
  }
}

// ============================ HOST ============================

extern "C" void kernel_launch(void* const* d_in, const int* in_sizes, int n_in,
                              void* d_out, int out_size, void* d_ws, size_t ws_size,
                              hipStream_t stream) {
  const float* x  = (const float*)d_in[0];
  const float* Wg = (const float*)d_in[1];
  const float* bg = (const float*)d_in[2];
  const float* We = (const float*)d_in[3];
  const float* be = (const float*)d_in[4];
  float* out = (float*)d_out;

  char* p = (char*)d_ws;
  int*   counts = (int*)p;                 p += 256;
  int*   lists  = (int*)p;                 p += (size_t)16 * TOKENS * 4;  // 512 KB
  float* wlists = (float*)p;               p += (size_t)16 * TOKENS * 4;  // 512 KB
  int*   epacked = (int*)p;                p += (size_t)TOKENS * 4;       // 32 KB
  float2* wpair  = (float2*)p;             p += (size_t)TOKENS * 8;       // 64 KB
  int*   hist    = (int*)p;                p += 256 * 16 * 4;             // 16 KB
  unsigned short* xbuf = (unsigned short*)p; p += (size_t)TOKENS * KDIM * 2;       // 16 MB
  unsigned short* Webf = (unsigned short*)p; p += (size_t)NEXP * NDIM * KDIM * 2;  // 16 MB
  size_t need_mid = (size_t)(p - (char*)d_ws);
  float* part1 = (float*)p;                p += (size_t)TOKENS * NDIM * 4;         // 32 MB
  size_t need_fast = (size_t)(p - (char*)d_ws);

  dim3 ggrid(NDIM / 256, 16, 16);  // 4 N x 16 M (2048 cap) x 16 groups
  if (ws_size >= need_fast) {
    // plain-store A/B arm: no zero pass, no atomics, + combine
    gate_conv_kernel<<<4352, 256, 0, stream>>>(
        x, Wg, bg, We, xbuf, Webf, epacked, wpair, hist, out);
    scatter_kernel<<<256, 256, 0, stream>>>(hist, epacked, wpair, counts, lists, wlists);
    moe_gemm_wide<1><<<ggrid, 512, 0, stream>>>(
        xbuf, Webf, be, counts, lists, wlists, out, part1);
    combine_kernel<<<TOKENS * NDIM / 4 / 256, 256, 0, stream>>>(out, part1);
  } else if (ws_size >= need_mid) {
    // r13 atomic arm (pre-zeroed out via extra gate_conv blocks)
    gate_conv_kernel<<<5376, 256, 0, stream>>>(
        x, Wg, bg, We, xbuf, Webf, epacked, wpair, hist, out);
    scatter_kernel<<<256, 256, 0, stream>>>(hist, epacked, wpair, counts, lists, wlists);
    moe_gemm_wide<0><<<ggrid, 512, 0, stream>>>(
        xbuf, Webf, be, counts, lists, wlists, out, out);
  } else {
    dim3 grid(NDIM / 128, TOKENS / 128, NEXP);
    hipMemsetAsync(d_ws, 0, 64, stream);
    gate_kernel<<<TOKENS / 4, 256, 0, stream>>>(x, Wg, bg, counts, lists, wlists);
    moe_gemm<0><<<grid, 256, 0, stream>>>(x, We, be, counts, lists, wlists, out, 0);
    moe_gemm<1><<<grid, 256, 0, stream>>>(x, We, be, counts, lists, wlists, out, 1);
  }
}